// Round 6
// baseline (466.801 us; speedup 1.0000x reference)
//
#include <hip/hip_runtime.h>
#include <hip/hip_bf16.h>

#define H 4
#define C 64
#define D 256
#define NEG_SLOPE 0.2f
#define LCAP 256
#define ESHIFT 8.0f

typedef __attribute__((ext_vector_type(8))) short short8v;
typedef __attribute__((ext_vector_type(4))) float f32x4;
typedef unsigned short ushort_t;

__device__ inline ushort_t f2bf(float f) {
    __hip_bfloat16 h = __float2bfloat16(f);
    return *reinterpret_cast<ushort_t*>(&h);
}
__device__ inline float bf2f(ushort_t u) {
    __hip_bfloat16 h = *reinterpret_cast<__hip_bfloat16*>(&u);
    return __bfloat162float(h);
}

// ---------------- CSR build ----------------
__global__ void count_kernel(const int* __restrict__ ei, int E, int N, int* __restrict__ counts) {
    int i = blockIdx.x * blockDim.x + threadIdx.x;
    if (i >= E + N) return;
    int d = (i < E) ? ei[E + i] : (i - E);
    atomicAdd(&counts[d], 1);
}

__global__ __launch_bounds__(1024) void prefix_scan(const int* __restrict__ counts,
                                                    int* __restrict__ row_ptr,
                                                    int* __restrict__ cursor, int N) {
    __shared__ int wsum[16];
    __shared__ int carry_s;
    int tid = threadIdx.x, lane = tid & 63, wid = tid >> 6;
    if (tid == 0) carry_s = 0;
    __syncthreads();
    for (int base = 0; base < N; base += 1024) {
        int idx = base + tid;
        int v = (idx < N) ? counts[idx] : 0;
        int val = v;
        #pragma unroll
        for (int o = 1; o < 64; o <<= 1) {
            int t = __shfl_up(val, o);
            if (lane >= o) val += t;
        }
        if (lane == 63) wsum[wid] = val;
        __syncthreads();
        int woff = 0;
        #pragma unroll
        for (int w = 0; w < 16; w++) woff += (w < wid) ? wsum[w] : 0;
        int carry = carry_s;
        if (idx < N) {
            int excl = carry + woff + val - v;
            row_ptr[idx] = excl;
            cursor[idx] = excl;
        }
        __syncthreads();
        if (tid == 1023) carry_s = carry + woff + val;
        __syncthreads();
    }
    if (threadIdx.x == 0) row_ptr[N] = carry_s;
}

__global__ void scatter_kernel(const int* __restrict__ ei, int E, int N,
                               int* __restrict__ cursor, int* __restrict__ csr_src) {
    int i = blockIdx.x * blockDim.x + threadIdx.x;
    if (i >= E + N) return;
    int s, d;
    if (i < E) { s = ei[i]; d = ei[E + i]; }
    else       { s = d = i - E; }
    int pos = atomicAdd(&cursor[d], 1);
    csr_src[pos] = s;
}

// ---------------- fp32 -> bf16 hi/lo splits ----------------
__global__ void split_x(const float* __restrict__ in, ushort_t* __restrict__ hi,
                        ushort_t* __restrict__ lo, int n8) {
    int i = blockIdx.x * blockDim.x + threadIdx.x;
    if (i >= n8) return;
    float4 v0 = ((const float4*)in)[i * 2];
    float4 v1 = ((const float4*)in)[i * 2 + 1];
    float f[8] = {v0.x, v0.y, v0.z, v0.w, v1.x, v1.y, v1.z, v1.w};
    ushort_t hb[8] __attribute__((aligned(16)));
    ushort_t lb[8] __attribute__((aligned(16)));
    #pragma unroll
    for (int j = 0; j < 8; j++) {
        ushort_t h = f2bf(f[j]);
        hb[j] = h;
        lb[j] = f2bf(f[j] - bf2f(h));
    }
    ((uint4*)hi)[i] = *(uint4*)hb;
    ((uint4*)lo)[i] = *(uint4*)lb;
}

// W[l][k][col] -> Wt[l][col][k], split hi/lo
__global__ void split_w(const float* __restrict__ W, ushort_t* __restrict__ whi,
                        ushort_t* __restrict__ wlo, int total) {
    int i = blockIdx.x * blockDim.x + threadIdx.x;
    if (i >= total) return;
    int l = i >> 16;
    int rem = i & 65535;
    int col = rem >> 8;
    int k = rem & 255;
    float f = W[(l << 16) + (k << 8) + col];
    ushort_t h = f2bf(f);
    whi[i] = h;
    wlo[i] = f2bf(f - bf2f(h));
}

// ---------------- bf16x3 MFMA GEMM + fused attention scores ----------------
// grid (Npad/64, 4): block = 64 rows x one 64-col head-group; wave = 16 rows x 64 cols.
// 5008 waves total, ~120 VGPR -> 4 waves/SIMD resident: TLP hides load latency.
__global__ __launch_bounds__(256, 2) void gemm_bf16x3(
    const ushort_t* __restrict__ Ahi, const ushort_t* __restrict__ Alo,
    const ushort_t* __restrict__ Wthi, const ushort_t* __restrict__ Wtlo,
    const float* __restrict__ asrc, const float* __restrict__ adst,
    ushort_t* __restrict__ hp, float* __restrict__ as_out, float* __restrict__ ad_out) {
    int wv = threadIdx.x >> 6, lane = threadIdx.x & 63;
    int h = blockIdx.y;            // 64-col group == head
    int r0 = blockIdx.x * 64 + wv * 16;
    int rlo = lane & 15;
    int khi = (lane >> 4) << 3;
    const ushort_t* pa_hi = Ahi + (size_t)(r0 + rlo) * 256 + khi;
    const ushort_t* pa_lo = Alo + (size_t)(r0 + rlo) * 256 + khi;
    const ushort_t* pb_hi = Wthi + (size_t)(h * 64 + rlo) * 256 + khi;  // + cb*4096 + k0
    const ushort_t* pb_lo = Wtlo + (size_t)(h * 64 + rlo) * 256 + khi;

    f32x4 acc[4];
    #pragma unroll
    for (int cb = 0; cb < 4; cb++) acc[cb] = (f32x4){0.f, 0.f, 0.f, 0.f};

    short8v A0h, A0l, B0h[4], B0l[4];
    short8v A1h, A1l, B1h[4], B1l[4];

    // prologue: slab k=0
    A0h = *(const short8v*)(pa_hi);
    A0l = *(const short8v*)(pa_lo);
    #pragma unroll
    for (int i = 0; i < 4; i++) {
        B0h[i] = *(const short8v*)(pb_hi + i * 4096);
        B0l[i] = *(const short8v*)(pb_lo + i * 4096);
    }

    #pragma unroll
    for (int kk = 0; kk < 4; kk++) {
        const int k0 = kk * 64;
        // prefetch slab k0+32 into buf1
        A1h = *(const short8v*)(pa_hi + k0 + 32);
        A1l = *(const short8v*)(pa_lo + k0 + 32);
        #pragma unroll
        for (int i = 0; i < 4; i++) {
            B1h[i] = *(const short8v*)(pb_hi + i * 4096 + k0 + 32);
            B1l[i] = *(const short8v*)(pb_lo + i * 4096 + k0 + 32);
        }
        // MFMA on buf0
        #pragma unroll
        for (int cb = 0; cb < 4; cb++) {
            acc[cb] = __builtin_amdgcn_mfma_f32_16x16x32_bf16(A0h, B0h[cb], acc[cb], 0, 0, 0);
            acc[cb] = __builtin_amdgcn_mfma_f32_16x16x32_bf16(A0h, B0l[cb], acc[cb], 0, 0, 0);
            acc[cb] = __builtin_amdgcn_mfma_f32_16x16x32_bf16(A0l, B0h[cb], acc[cb], 0, 0, 0);
        }
        // prefetch slab k0+64 into buf0 (skip on last)
        if (kk < 3) {
            A0h = *(const short8v*)(pa_hi + k0 + 64);
            A0l = *(const short8v*)(pa_lo + k0 + 64);
            #pragma unroll
            for (int i = 0; i < 4; i++) {
                B0h[i] = *(const short8v*)(pb_hi + i * 4096 + k0 + 64);
                B0l[i] = *(const short8v*)(pb_lo + i * 4096 + k0 + 64);
            }
        }
        // MFMA on buf1
        #pragma unroll
        for (int cb = 0; cb < 4; cb++) {
            acc[cb] = __builtin_amdgcn_mfma_f32_16x16x32_bf16(A1h, B1h[cb], acc[cb], 0, 0, 0);
            acc[cb] = __builtin_amdgcn_mfma_f32_16x16x32_bf16(A1h, B1l[cb], acc[cb], 0, 0, 0);
            acc[cb] = __builtin_amdgcn_mfma_f32_16x16x32_bf16(A1l, B1h[cb], acc[cb], 0, 0, 0);
        }
    }

    // C/D layout: col = h*64 + cb*16 + rlo, row = r0 + (lane>>4)*4 + i
    int rbase = r0 + ((lane >> 4) << 2);
    #pragma unroll
    for (int cb = 0; cb < 4; cb++) {
        #pragma unroll
        for (int i = 0; i < 4; i++)
            hp[(size_t)(rbase + i) * 256 + h * 64 + cb * 16 + rlo] = f2bf(acc[cb][i]);
    }

    // fused a_s/a_d for this head
    {
        float ps[4] = {0.f, 0.f, 0.f, 0.f};
        float pd[4] = {0.f, 0.f, 0.f, 0.f};
        #pragma unroll
        for (int cb = 0; cb < 4; cb++) {
            float av = asrc[h * 64 + cb * 16 + rlo];
            float dv = adst[h * 64 + cb * 16 + rlo];
            #pragma unroll
            for (int i = 0; i < 4; i++) {
                ps[i] += acc[cb][i] * av;
                pd[i] += acc[cb][i] * dv;
            }
        }
        #pragma unroll
        for (int mask = 1; mask <= 8; mask <<= 1) {
            #pragma unroll
            for (int i = 0; i < 4; i++) {
                ps[i] += __shfl_xor(ps[i], mask);
                pd[i] += __shfl_xor(pd[i], mask);
            }
        }
        if (rlo == 0) {
            #pragma unroll
            for (int i = 0; i < 4; i++) {
                as_out[(size_t)(rbase + i) * 4 + h] = ps[i];
                ad_out[(size_t)(rbase + i) * 4 + h] = pd[i];
            }
        }
    }
}

// ---------------- GAT aggregation v4: 4-edge-slot x ushort4 gather (8 loads in flight) ----------------
__global__ __launch_bounds__(256) void gat_aggregate4(
    const ushort_t* __restrict__ hp, const float* __restrict__ as_, const float* __restrict__ ad_,
    const int* __restrict__ row_ptr, const int* __restrict__ csr_src,
    const float* __restrict__ bias, float* hf32,
    ushort_t* hhi, ushort_t* hlo, int write_f32) {
    __shared__ float lds_e[4][LCAP];
    __shared__ int   lds_s[4][LCAP];
    int d = blockIdx.x;
    int h = threadIdx.x >> 6, lane = threadIdx.x & 63;
    int r0 = row_ptr[d], deg = row_ptr[d + 1] - r0;
    float adv = ad_[d * 4 + h];

    if (deg <= LCAP) {
        // phase A: lane-parallel exp + denom (fixed shift cancels in normalization)
        float ssum = 0.f;
        for (int i = lane; i < deg; i += 64) {
            int s = csr_src[r0 + i];
            float e = as_[s * 4 + h] + adv;
            e = e > 0.f ? e : NEG_SLOPE * e;
            float ex = __expf(e - ESHIFT);
            lds_s[h][i] = s;
            lds_e[h][i] = ex;
            ssum += ex;
        }
        #pragma unroll
        for (int o = 32; o; o >>= 1) ssum += __shfl_xor(ssum, o);
        float inv = 1.0f / ssum;

        // phase B: lane = (edge_slot es 0..3, channel-quad chq 0..15); 8 gathers in flight
        int es = lane >> 4, chq = lane & 15;
        const ushort_t* hpb = hp + h * 64 + chq * 4;
        float a0c = 0.f, a1c = 0.f, a2c = 0.f, a3c = 0.f;
        for (int i = 0; i < deg; i += 8) {
            int e0 = i + es, e1 = i + 4 + es;
            bool v0 = e0 < deg, v1 = e1 < deg;
            int s0 = v0 ? lds_s[h][e0] : 0;
            int s1 = v1 ? lds_s[h][e1] : 0;
            float a0 = v0 ? lds_e[h][e0] : 0.f;
            float a1 = v1 ? lds_e[h][e1] : 0.f;
            ushort4 u0 = *(const ushort4*)(hpb + (size_t)s0 * 256);
            ushort4 u1 = *(const ushort4*)(hpb + (size_t)s1 * 256);
            a0c += a0 * bf2f(u0.x) + a1 * bf2f(u1.x);
            a1c += a0 * bf2f(u0.y) + a1 * bf2f(u1.y);
            a2c += a0 * bf2f(u0.z) + a1 * bf2f(u1.z);
            a3c += a0 * bf2f(u0.w) + a1 * bf2f(u1.w);
        }
        // reduce across the 4 edge slots
        #pragma unroll
        for (int o = 16; o <= 32; o <<= 1) {
            a0c += __shfl_xor(a0c, o);
            a1c += __shfl_xor(a1c, o);
            a2c += __shfl_xor(a2c, o);
            a3c += __shfl_xor(a3c, o);
        }
        if (es == 0) {
            float vv[4] = {a0c, a1c, a2c, a3c};
            size_t base = (size_t)d * 256 + h * 64 + chq * 4;
            if (write_f32) {
                float4 o4;
                float* po = (float*)&o4;
                #pragma unroll
                for (int j = 0; j < 4; j++) {
                    float v = vv[j] * inv + bias[h * 64 + chq * 4 + j];
                    po[j] = v > 0.f ? v : (__expf(v) - 1.0f);
                }
                *(float4*)&hf32[base] = o4;
            } else {
                ushort4 oh, ol;
                ushort_t* ph = (ushort_t*)&oh;
                ushort_t* pl = (ushort_t*)&ol;
                #pragma unroll
                for (int j = 0; j < 4; j++) {
                    float v = vv[j] * inv + bias[h * 64 + chq * 4 + j];
                    v = v > 0.f ? v : (__expf(v) - 1.0f);
                    ushort_t hb = f2bf(v);
                    ph[j] = hb;
                    pl[j] = f2bf(v - bf2f(hb));
                }
                *(ushort4*)&hhi[base] = oh;
                *(ushort4*)&hlo[base] = ol;
            }
        }
    } else {
        // fallback: recompute path (deg > LCAP; not expected with this data)
        float ssum = 0.f;
        for (int i = lane; i < deg; i += 64) {
            int s = csr_src[r0 + i];
            float e = as_[s * 4 + h] + adv;
            e = e > 0.f ? e : NEG_SLOPE * e;
            ssum += __expf(e - ESHIFT);
        }
        #pragma unroll
        for (int o = 32; o; o >>= 1) ssum += __shfl_xor(ssum, o);
        float inv = 1.0f / ssum;
        float acc = 0.f;
        for (int i = 0; i < deg; i++) {
            int s = csr_src[r0 + i];
            float e = as_[s * 4 + h] + adv;
            e = e > 0.f ? e : NEG_SLOPE * e;
            acc += __expf(e - ESHIFT) * bf2f(hp[(size_t)s * 256 + h * 64 + lane]);
        }
        float v = acc * inv + bias[h * 64 + lane];
        v = v > 0.f ? v : (__expf(v) - 1.0f);
        size_t idx = (size_t)d * 256 + h * 64 + lane;
        if (write_f32) {
            hf32[idx] = v;
        } else {
            ushort_t hb = f2bf(v);
            hhi[idx] = hb;
            hlo[idx] = f2bf(v - bf2f(hb));
        }
    }
}

// ---------------- pooling + output head ----------------
__global__ __launch_bounds__(256) void col_sum(const float* __restrict__ hin,
                                               float* __restrict__ g, int N, int rows_per_blk) {
    int c = threadIdx.x;
    int r0 = blockIdx.x * rows_per_blk;
    int r1 = min(r0 + rows_per_blk, N);
    float acc = 0.f;
    for (int r = r0; r < r1; r++) acc += hin[(size_t)r * D + c];
    atomicAdd(&g[c], acc);
}

__global__ __launch_bounds__(256) void final_kernel(const float* __restrict__ g,
                                                    const float* __restrict__ Wout,
                                                    const float* __restrict__ bout,
                                                    float* __restrict__ out, float invN) {
    int j = threadIdx.x;
    float acc = 0.f;
    for (int i = 0; i < D; i++) acc += g[i] * Wout[i * D + j];
    out[j] = acc * invN + bout[j];
}

extern "C" void kernel_launch(void* const* d_in, const int* in_sizes, int n_in,
                              void* d_out, int out_size, void* d_ws, size_t ws_size,
                              hipStream_t stream) {
    const float* x       = (const float*)d_in[0];
    const int*   ei      = (const int*)d_in[1];
    const float* Ws      = (const float*)d_in[2];
    const float* att_src = (const float*)d_in[3];
    const float* att_dst = (const float*)d_in[4];
    const float* biases  = (const float*)d_in[5];
    const float* Wout    = (const float*)d_in[6];
    const float* bout    = (const float*)d_in[7];
    float* out = (float*)d_out;

    int N = in_sizes[0] / D;          // 20000
    int E = in_sizes[1] / 2;          // 320000
    int L = in_sizes[2] / (D * D);    // 4
    int Etot = E + N;
    int Npad = (N + 63) & ~63;        // 20032 = 313 * 64

    char* ws = (char*)d_ws;
    size_t off = 0;
    auto alloc = [&](size_t bytes) -> void* {
        void* p = ws + off;
        off = (off + bytes + 255) & ~(size_t)255;
        return p;
    };
    ushort_t* shi  = (ushort_t*)alloc((size_t)Npad * D * 2);
    ushort_t* slo  = (ushort_t*)alloc((size_t)Npad * D * 2);
    ushort_t* hp   = (ushort_t*)alloc((size_t)Npad * D * 2);
    float* a_s     = (float*)alloc((size_t)Npad * H * 4);
    float* a_d     = (float*)alloc((size_t)Npad * H * 4);
    ushort_t* wthi = (ushort_t*)alloc((size_t)L * D * D * 2);
    ushort_t* wtlo = (ushort_t*)alloc((size_t)L * D * D * 2);
    float* g       = (float*)alloc(D * 4);
    int*   counts  = (int*)alloc((size_t)N * 4);
    int*   row_ptr = (int*)alloc((size_t)(N + 1) * 4);
    int*   cursor  = (int*)alloc((size_t)N * 4);
    int*   csr_src = (int*)alloc((size_t)Etot * 4);
    float* hf32 = (float*)shi;   // last-layer h (f32) aliases shi+slo (contiguous, 2x bf16 = f32 size)
    if (off > ws_size) return;

    int thr = 256;

    // ---- splits ----
    int n8 = N * D / 8;
    split_x<<<(n8 + thr - 1) / thr, thr, 0, stream>>>(x, shi, slo, n8);
    int wtot = L * D * D;
    split_w<<<(wtot + thr - 1) / thr, thr, 0, stream>>>(Ws, wthi, wtlo, wtot);

    // ---- CSR build ----
    hipMemsetAsync(counts, 0, (size_t)N * 4, stream);
    count_kernel<<<(Etot + thr - 1) / thr, thr, 0, stream>>>(ei, E, N, counts);
    prefix_scan<<<1, 1024, 0, stream>>>(counts, row_ptr, cursor, N);
    scatter_kernel<<<(Etot + thr - 1) / thr, thr, 0, stream>>>(ei, E, N, cursor, csr_src);

    // ---- layers ----
    dim3 ggrid(Npad / 64, 4);
    for (int l = 0; l < L; l++) {
        gemm_bf16x3<<<ggrid, 256, 0, stream>>>(
            shi, slo, wthi + (size_t)l * D * D, wtlo + (size_t)l * D * D,
            att_src + (size_t)l * H * C, att_dst + (size_t)l * H * C,
            hp, a_s, a_d);
        gat_aggregate4<<<N, 256, 0, stream>>>(
            hp, a_s, a_d, row_ptr, csr_src, biases + (size_t)l * D,
            hf32, shi, slo, (l == L - 1) ? 1 : 0);
    }

    // ---- pool + head ----
    hipMemsetAsync(g, 0, D * 4, stream);
    int rows_per_blk = 100;
    col_sum<<<(N + rows_per_blk - 1) / rows_per_blk, thr, 0, stream>>>(hf32, g, N, rows_per_blk);
    final_kernel<<<1, thr, 0, stream>>>(g, Wout, bout, out, 1.0f / (float)N);
}

// Round 7
// 396.047 us; speedup vs baseline: 1.1786x; 1.1786x over previous
//
#include <hip/hip_runtime.h>
#include <hip/hip_bf16.h>

#define H 4
#define C 64
#define D 256
#define NEG_SLOPE 0.2f
#define LCAP 256
#define ESHIFT 8.0f

typedef _Float16 half_t;
typedef __attribute__((ext_vector_type(8))) _Float16 half8v;
typedef __attribute__((ext_vector_type(4))) _Float16 half4v;
typedef __attribute__((ext_vector_type(4))) float f32x4;
typedef unsigned short ushort_t;

// ---------------- CSR build ----------------
__global__ void count_kernel(const int* __restrict__ ei, int E, int N, int* __restrict__ counts) {
    int i = blockIdx.x * blockDim.x + threadIdx.x;
    if (i >= E + N) return;
    int d = (i < E) ? ei[E + i] : (i - E);
    atomicAdd(&counts[d], 1);
}

__global__ __launch_bounds__(1024) void prefix_scan(const int* __restrict__ counts,
                                                    int* __restrict__ row_ptr,
                                                    int* __restrict__ cursor, int N) {
    __shared__ int wsum[16];
    __shared__ int carry_s;
    int tid = threadIdx.x, lane = tid & 63, wid = tid >> 6;
    if (tid == 0) carry_s = 0;
    __syncthreads();
    for (int base = 0; base < N; base += 1024) {
        int idx = base + tid;
        int v = (idx < N) ? counts[idx] : 0;
        int val = v;
        #pragma unroll
        for (int o = 1; o < 64; o <<= 1) {
            int t = __shfl_up(val, o);
            if (lane >= o) val += t;
        }
        if (lane == 63) wsum[wid] = val;
        __syncthreads();
        int woff = 0;
        #pragma unroll
        for (int w = 0; w < 16; w++) woff += (w < wid) ? wsum[w] : 0;
        int carry = carry_s;
        if (idx < N) {
            int excl = carry + woff + val - v;
            row_ptr[idx] = excl;
            cursor[idx] = excl;
        }
        __syncthreads();
        if (tid == 1023) carry_s = carry + woff + val;
        __syncthreads();
    }
    if (threadIdx.x == 0) row_ptr[N] = carry_s;
}

__global__ void scatter_kernel(const int* __restrict__ ei, int E, int N,
                               int* __restrict__ cursor, int* __restrict__ csr_src) {
    int i = blockIdx.x * blockDim.x + threadIdx.x;
    if (i >= E + N) return;
    int s, d;
    if (i < E) { s = ei[i]; d = ei[E + i]; }
    else       { s = d = i - E; }
    int pos = atomicAdd(&cursor[d], 1);
    csr_src[pos] = s;
}

// ---------------- fp32 -> f16 conversions ----------------
__global__ void conv_x(const float* __restrict__ in, half_t* __restrict__ outh, int n8) {
    int i = blockIdx.x * blockDim.x + threadIdx.x;
    if (i >= n8) return;
    float4 v0 = ((const float4*)in)[i * 2];
    float4 v1 = ((const float4*)in)[i * 2 + 1];
    half_t o[8] __attribute__((aligned(16)));
    o[0] = (half_t)v0.x; o[1] = (half_t)v0.y; o[2] = (half_t)v0.z; o[3] = (half_t)v0.w;
    o[4] = (half_t)v1.x; o[5] = (half_t)v1.y; o[6] = (half_t)v1.z; o[7] = (half_t)v1.w;
    ((uint4*)outh)[i] = *(uint4*)o;
}

// W[l][k][col] -> Wt[l][col][k] (f16)
__global__ void conv_w(const float* __restrict__ W, half_t* __restrict__ wt, int total) {
    int i = blockIdx.x * blockDim.x + threadIdx.x;
    if (i >= total) return;
    int l = i >> 16;
    int rem = i & 65535;
    int col = rem >> 8;
    int k = rem & 255;
    wt[i] = (half_t)W[(l << 16) + (k << 8) + col];
}

// ---------------- f16 single-pass MFMA GEMM + fused attention scores ----------------
// grid Npad/64; block 256 thr = 4 waves; wave = head = 64 rows x 64 cols.
// All 4 waves share the same 64 A-rows (L1-resident); W f16 L2-resident.
__global__ __launch_bounds__(256) void gemm_f16(
    const half_t* __restrict__ Af, const half_t* __restrict__ Wt,
    const float* __restrict__ asrc, const float* __restrict__ adst,
    half_t* __restrict__ hp, float* __restrict__ as_out, float* __restrict__ ad_out) {
    int wv = threadIdx.x >> 6, lane = threadIdx.x & 63;
    int h = wv;                    // wave == head (64-col group)
    int r0 = blockIdx.x * 64;
    int rlo = lane & 15;
    int khi = (lane >> 4) << 3;
    const half_t* pa = Af + (size_t)(r0 + rlo) * 256 + khi;        // + rf*4096 + k0
    const half_t* pb = Wt + (size_t)(h * 64 + rlo) * 256 + khi;    // + cb*4096 + k0

    f32x4 acc[4][4];
    #pragma unroll
    for (int rf = 0; rf < 4; rf++)
        #pragma unroll
        for (int cb = 0; cb < 4; cb++) acc[rf][cb] = (f32x4){0.f, 0.f, 0.f, 0.f};

    half8v A0[4], B0[4], A1[4], B1[4];

    // prologue: slab k=0
    #pragma unroll
    for (int i = 0; i < 4; i++) {
        A0[i] = *(const half8v*)(pa + i * 4096);
        B0[i] = *(const half8v*)(pb + i * 4096);
    }

    #pragma unroll
    for (int kk = 0; kk < 4; kk++) {
        const int k0 = kk * 64;
        // prefetch slab k0+32 into buf1
        #pragma unroll
        for (int i = 0; i < 4; i++) {
            A1[i] = *(const half8v*)(pa + i * 4096 + k0 + 32);
            B1[i] = *(const half8v*)(pb + i * 4096 + k0 + 32);
        }
        // MFMA on buf0
        #pragma unroll
        for (int rf = 0; rf < 4; rf++)
            #pragma unroll
            for (int cb = 0; cb < 4; cb++)
                acc[rf][cb] = __builtin_amdgcn_mfma_f32_16x16x32_f16(A0[rf], B0[cb], acc[rf][cb], 0, 0, 0);
        // prefetch slab k0+64 into buf0 (skip on last)
        if (kk < 3) {
            #pragma unroll
            for (int i = 0; i < 4; i++) {
                A0[i] = *(const half8v*)(pa + i * 4096 + k0 + 64);
                B0[i] = *(const half8v*)(pb + i * 4096 + k0 + 64);
            }
        }
        // MFMA on buf1
        #pragma unroll
        for (int rf = 0; rf < 4; rf++)
            #pragma unroll
            for (int cb = 0; cb < 4; cb++)
                acc[rf][cb] = __builtin_amdgcn_mfma_f32_16x16x32_f16(A1[rf], B1[cb], acc[rf][cb], 0, 0, 0);
    }

    // C/D layout: col = h*64 + cb*16 + rlo, row = r0 + rf*16 + (lane>>4)*4 + i
    #pragma unroll
    for (int rf = 0; rf < 4; rf++) {
        int rbase = r0 + rf * 16 + ((lane >> 4) << 2);
        #pragma unroll
        for (int cb = 0; cb < 4; cb++) {
            #pragma unroll
            for (int i = 0; i < 4; i++)
                hp[(size_t)(rbase + i) * 256 + h * 64 + cb * 16 + rlo] = (half_t)acc[rf][cb][i];
        }
    }

    // fused a_s/a_d for this wave's head
    #pragma unroll
    for (int rf = 0; rf < 4; rf++) {
        float ps[4] = {0.f, 0.f, 0.f, 0.f};
        float pd[4] = {0.f, 0.f, 0.f, 0.f};
        #pragma unroll
        for (int cb = 0; cb < 4; cb++) {
            float av = asrc[h * 64 + cb * 16 + rlo];
            float dv = adst[h * 64 + cb * 16 + rlo];
            #pragma unroll
            for (int i = 0; i < 4; i++) {
                ps[i] += acc[rf][cb][i] * av;
                pd[i] += acc[rf][cb][i] * dv;
            }
        }
        #pragma unroll
        for (int mask = 1; mask <= 8; mask <<= 1) {
            #pragma unroll
            for (int i = 0; i < 4; i++) {
                ps[i] += __shfl_xor(ps[i], mask);
                pd[i] += __shfl_xor(pd[i], mask);
            }
        }
        if (rlo == 0) {
            int rbase = r0 + rf * 16 + ((lane >> 4) << 2);
            #pragma unroll
            for (int i = 0; i < 4; i++) {
                as_out[(size_t)(rbase + i) * 4 + h] = ps[i];
                ad_out[(size_t)(rbase + i) * 4 + h] = pd[i];
            }
        }
    }
}

// ---------------- GAT aggregation: f16 gather, 16 loads in flight ----------------
__global__ __launch_bounds__(256) void gat_aggregate(
    const half_t* __restrict__ hp, const float* __restrict__ as_, const float* __restrict__ ad_,
    const int* __restrict__ row_ptr, const int* __restrict__ csr_src,
    const float* __restrict__ bias, float* __restrict__ hf32,
    half_t* __restrict__ hnext, int write_f32) {
    __shared__ float lds_e[4][LCAP];
    __shared__ int   lds_s[4][LCAP];
    int d = blockIdx.x;
    int h = threadIdx.x >> 6, lane = threadIdx.x & 63;
    int r0 = row_ptr[d], deg = row_ptr[d + 1] - r0;
    float adv = ad_[d * 4 + h];

    if (deg <= LCAP) {
        // phase A: lane-parallel exp + denom (fixed shift cancels in normalization)
        float ssum = 0.f;
        for (int i = lane; i < deg; i += 64) {
            int s = csr_src[r0 + i];
            float e = as_[s * 4 + h] + adv;
            e = e > 0.f ? e : NEG_SLOPE * e;
            float ex = __expf(e - ESHIFT);
            lds_s[h][i] = s;
            lds_e[h][i] = ex;
            ssum += ex;
        }
        #pragma unroll
        for (int o = 32; o; o >>= 1) ssum += __shfl_xor(ssum, o);
        float inv = 1.0f / ssum;

        // phase B: lane = (edge_slot es 0..3, channel-quad chq 0..15); 4-deep unroll -> 16 loads in flight
        int es = lane >> 4, chq = lane & 15;
        const half_t* hpb = hp + h * 64 + chq * 4;
        float c0 = 0.f, c1 = 0.f, c2 = 0.f, c3 = 0.f;
        for (int i = 0; i < deg; i += 16) {
            #pragma unroll
            for (int u = 0; u < 4; u++) {
                int e = i + u * 4 + es;
                if (e < deg) {
                    int s = lds_s[h][e];
                    float a = lds_e[h][e];
                    half4v q = *(const half4v*)(hpb + (size_t)s * 256);
                    c0 += a * (float)q[0];
                    c1 += a * (float)q[1];
                    c2 += a * (float)q[2];
                    c3 += a * (float)q[3];
                }
            }
        }
        // reduce across the 4 edge slots
        #pragma unroll
        for (int o = 16; o <= 32; o <<= 1) {
            c0 += __shfl_xor(c0, o);
            c1 += __shfl_xor(c1, o);
            c2 += __shfl_xor(c2, o);
            c3 += __shfl_xor(c3, o);
        }
        if (es == 0) {
            float vv[4] = {c0, c1, c2, c3};
            size_t base = (size_t)d * 256 + h * 64 + chq * 4;
            if (write_f32) {
                float4 o4;
                float* po = (float*)&o4;
                #pragma unroll
                for (int j = 0; j < 4; j++) {
                    float v = vv[j] * inv + bias[h * 64 + chq * 4 + j];
                    po[j] = v > 0.f ? v : (__expf(v) - 1.0f);
                }
                *(float4*)&hf32[base] = o4;
            } else {
                half_t oh[4] __attribute__((aligned(8)));
                #pragma unroll
                for (int j = 0; j < 4; j++) {
                    float v = vv[j] * inv + bias[h * 64 + chq * 4 + j];
                    v = v > 0.f ? v : (__expf(v) - 1.0f);
                    oh[j] = (half_t)v;
                }
                *(half4v*)&hnext[base] = *(half4v*)oh;
            }
        }
    } else {
        // fallback: recompute path (deg > LCAP; not expected with this data)
        float ssum = 0.f;
        for (int i = lane; i < deg; i += 64) {
            int s = csr_src[r0 + i];
            float e = as_[s * 4 + h] + adv;
            e = e > 0.f ? e : NEG_SLOPE * e;
            ssum += __expf(e - ESHIFT);
        }
        #pragma unroll
        for (int o = 32; o; o >>= 1) ssum += __shfl_xor(ssum, o);
        float inv = 1.0f / ssum;
        float acc = 0.f;
        for (int i = 0; i < deg; i++) {
            int s = csr_src[r0 + i];
            float e = as_[s * 4 + h] + adv;
            e = e > 0.f ? e : NEG_SLOPE * e;
            acc += __expf(e - ESHIFT) * (float)hp[(size_t)s * 256 + h * 64 + lane];
        }
        float v = acc * inv + bias[h * 64 + lane];
        v = v > 0.f ? v : (__expf(v) - 1.0f);
        size_t idx = (size_t)d * 256 + h * 64 + lane;
        if (write_f32) hf32[idx] = v;
        else           hnext[idx] = (half_t)v;
    }
}

// ---------------- pooling + output head ----------------
__global__ __launch_bounds__(256) void col_sum(const float* __restrict__ hin,
                                               float* __restrict__ g, int N, int rows_per_blk) {
    int c = threadIdx.x;
    int r0 = blockIdx.x * rows_per_blk;
    int r1 = min(r0 + rows_per_blk, N);
    float acc = 0.f;
    for (int r = r0; r < r1; r++) acc += hin[(size_t)r * D + c];
    atomicAdd(&g[c], acc);
}

__global__ __launch_bounds__(256) void final_kernel(const float* __restrict__ g,
                                                    const float* __restrict__ Wout,
                                                    const float* __restrict__ bout,
                                                    float* __restrict__ out, float invN) {
    int j = threadIdx.x;
    float acc = 0.f;
    for (int i = 0; i < D; i++) acc += g[i] * Wout[i * D + j];
    out[j] = acc * invN + bout[j];
}

extern "C" void kernel_launch(void* const* d_in, const int* in_sizes, int n_in,
                              void* d_out, int out_size, void* d_ws, size_t ws_size,
                              hipStream_t stream) {
    const float* x       = (const float*)d_in[0];
    const int*   ei      = (const int*)d_in[1];
    const float* Ws      = (const float*)d_in[2];
    const float* att_src = (const float*)d_in[3];
    const float* att_dst = (const float*)d_in[4];
    const float* biases  = (const float*)d_in[5];
    const float* Wout    = (const float*)d_in[6];
    const float* bout    = (const float*)d_in[7];
    float* out = (float*)d_out;

    int N = in_sizes[0] / D;          // 20000
    int E = in_sizes[1] / 2;          // 320000
    int L = in_sizes[2] / (D * D);    // 4
    int Etot = E + N;
    int Npad = (N + 63) & ~63;        // 20032 = 313 * 64

    char* ws = (char*)d_ws;
    size_t off = 0;
    auto alloc = [&](size_t bytes) -> void* {
        void* p = ws + off;
        off = (off + bytes + 255) & ~(size_t)255;
        return p;
    };
    half_t* xf16   = (half_t*)alloc((size_t)Npad * D * 2);
    half_t* hp     = (half_t*)alloc((size_t)Npad * D * 2);
    float* a_s     = (float*)alloc((size_t)Npad * H * 4);
    float* a_d     = (float*)alloc((size_t)Npad * H * 4);
    half_t* wt     = (half_t*)alloc((size_t)L * D * D * 2);
    float* hf32    = (float*)alloc((size_t)Npad * D * 4);
    float* g       = (float*)alloc(D * 4);
    int*   counts  = (int*)alloc((size_t)N * 4);
    int*   row_ptr = (int*)alloc((size_t)(N + 1) * 4);
    int*   cursor  = (int*)alloc((size_t)N * 4);
    int*   csr_src = (int*)alloc((size_t)Etot * 4);
    if (off > ws_size) return;

    int thr = 256;

    // ---- conversions ----
    int n8 = N * D / 8;
    conv_x<<<(n8 + thr - 1) / thr, thr, 0, stream>>>(x, xf16, n8);
    int wtot = L * D * D;
    conv_w<<<(wtot + thr - 1) / thr, thr, 0, stream>>>(Ws, wt, wtot);

    // ---- CSR build ----
    hipMemsetAsync(counts, 0, (size_t)N * 4, stream);
    count_kernel<<<(Etot + thr - 1) / thr, thr, 0, stream>>>(ei, E, N, counts);
    prefix_scan<<<1, 1024, 0, stream>>>(counts, row_ptr, cursor, N);
    scatter_kernel<<<(Etot + thr - 1) / thr, thr, 0, stream>>>(ei, E, N, cursor, csr_src);

    // ---- layers ----
    int gemm_blocks = Npad / 64;      // 313
    for (int l = 0; l < L; l++) {
        gemm_f16<<<gemm_blocks, 256, 0, stream>>>(
            xf16, wt + (size_t)l * D * D,
            att_src + (size_t)l * H * C, att_dst + (size_t)l * H * C,
            hp, a_s, a_d);
        gat_aggregate<<<N, 256, 0, stream>>>(
            hp, a_s, a_d, row_ptr, csr_src, biases + (size_t)l * D,
            hf32, xf16, (l == L - 1) ? 1 : 0);
    }

    // ---- pool + head ----
    hipMemsetAsync(g, 0, D * 4, stream);
    int rows_per_blk = 100;
    col_sum<<<(N + rows_per_blk - 1) / rows_per_blk, thr, 0, stream>>>(hf32, g, N, rows_per_blk);
    final_kernel<<<1, thr, 0, stream>>>(g, Wout, bout, out, 1.0f / (float)N);
}

// Round 8
// 390.229 us; speedup vs baseline: 1.1962x; 1.0149x over previous
//
#include <hip/hip_runtime.h>
#include <hip/hip_bf16.h>

#define H 4
#define C 64
#define D 256
#define NEG_SLOPE 0.2f
#define LCAP 256
#define ESHIFT 8.0f

typedef _Float16 half_t;
typedef __attribute__((ext_vector_type(8))) _Float16 half8v;
typedef __attribute__((ext_vector_type(4))) float f32x4;

// ---------------- CSR build ----------------
__global__ void count_kernel(const int* __restrict__ ei, int E, int N, int* __restrict__ counts) {
    int i = blockIdx.x * blockDim.x + threadIdx.x;
    if (i >= E + N) return;
    int d = (i < E) ? ei[E + i] : (i - E);
    atomicAdd(&counts[d], 1);
}

__global__ __launch_bounds__(1024) void prefix_scan(const int* __restrict__ counts,
                                                    int* __restrict__ row_ptr,
                                                    int* __restrict__ cursor, int N) {
    __shared__ int wsum[16];
    __shared__ int carry_s;
    int tid = threadIdx.x, lane = tid & 63, wid = tid >> 6;
    if (tid == 0) carry_s = 0;
    __syncthreads();
    for (int base = 0; base < N; base += 1024) {
        int idx = base + tid;
        int v = (idx < N) ? counts[idx] : 0;
        int val = v;
        #pragma unroll
        for (int o = 1; o < 64; o <<= 1) {
            int t = __shfl_up(val, o);
            if (lane >= o) val += t;
        }
        if (lane == 63) wsum[wid] = val;
        __syncthreads();
        int woff = 0;
        #pragma unroll
        for (int w = 0; w < 16; w++) woff += (w < wid) ? wsum[w] : 0;
        int carry = carry_s;
        if (idx < N) {
            int excl = carry + woff + val - v;
            row_ptr[idx] = excl;
            cursor[idx] = excl;
        }
        __syncthreads();
        if (tid == 1023) carry_s = carry + woff + val;
        __syncthreads();
    }
    if (threadIdx.x == 0) row_ptr[N] = carry_s;
}

__global__ void scatter_kernel(const int* __restrict__ ei, int E, int N,
                               int* __restrict__ cursor, int* __restrict__ csr_src) {
    int i = blockIdx.x * blockDim.x + threadIdx.x;
    if (i >= E + N) return;
    int s, d;
    if (i < E) { s = ei[i]; d = ei[E + i]; }
    else       { s = d = i - E; }
    int pos = atomicAdd(&cursor[d], 1);
    csr_src[pos] = s;
}

// ---------------- fp32 -> f16 conversions ----------------
__global__ void conv_x(const float* __restrict__ in, half_t* __restrict__ outh, int n8) {
    int i = blockIdx.x * blockDim.x + threadIdx.x;
    if (i >= n8) return;
    float4 v0 = ((const float4*)in)[i * 2];
    float4 v1 = ((const float4*)in)[i * 2 + 1];
    half_t o[8] __attribute__((aligned(16)));
    o[0] = (half_t)v0.x; o[1] = (half_t)v0.y; o[2] = (half_t)v0.z; o[3] = (half_t)v0.w;
    o[4] = (half_t)v1.x; o[5] = (half_t)v1.y; o[6] = (half_t)v1.z; o[7] = (half_t)v1.w;
    ((uint4*)outh)[i] = *(uint4*)o;
}

// W[l][k][col] -> Wt[l][col][k] (f16)
__global__ void conv_w(const float* __restrict__ W, half_t* __restrict__ wt, int total) {
    int i = blockIdx.x * blockDim.x + threadIdx.x;
    if (i >= total) return;
    int l = i >> 16;
    int rem = i & 65535;
    int col = rem >> 8;
    int k = rem & 255;
    wt[i] = (half_t)W[(l << 16) + (k << 8) + col];
}

// ---------------- f16 MFMA GEMM + fused attention scores ----------------
// grid Npad/16 (=1252) blocks; block = 16 rows x 256 cols; wave = head = 16 rows x 64 cols.
// 4 waves share the block's 16 A-rows (fetched once); ~4.9 blocks/CU -> ~5 waves/SIMD TLP.
__global__ __launch_bounds__(256) void gemm_f16(
    const half_t* __restrict__ Af, const half_t* __restrict__ Wt,
    const float* __restrict__ asrc, const float* __restrict__ adst,
    half_t* __restrict__ hp, float* __restrict__ as_out, float* __restrict__ ad_out) {
    int wv = threadIdx.x >> 6, lane = threadIdx.x & 63;
    int h = wv;                    // wave == head (64-col group)
    int r0 = blockIdx.x * 16;
    int rlo = lane & 15;
    int khi = (lane >> 4) << 3;
    const half_t* pa = Af + (size_t)(r0 + rlo) * 256 + khi;        // + k0
    const half_t* pb = Wt + (size_t)(h * 64 + rlo) * 256 + khi;    // + cb*4096 + k0

    f32x4 acc[4];
    #pragma unroll
    for (int cb = 0; cb < 4; cb++) acc[cb] = (f32x4){0.f, 0.f, 0.f, 0.f};

    half8v A0, B0[4], A1, B1[4];

    // prologue: slab k=0
    A0 = *(const half8v*)(pa);
    #pragma unroll
    for (int i = 0; i < 4; i++) B0[i] = *(const half8v*)(pb + i * 4096);

    #pragma unroll
    for (int kk = 0; kk < 4; kk++) {
        const int k0 = kk * 64;
        // prefetch slab k0+32
        A1 = *(const half8v*)(pa + k0 + 32);
        #pragma unroll
        for (int i = 0; i < 4; i++) B1[i] = *(const half8v*)(pb + i * 4096 + k0 + 32);
        // MFMA on buf0
        #pragma unroll
        for (int cb = 0; cb < 4; cb++)
            acc[cb] = __builtin_amdgcn_mfma_f32_16x16x32_f16(A0, B0[cb], acc[cb], 0, 0, 0);
        // prefetch slab k0+64 (skip on last)
        if (kk < 3) {
            A0 = *(const half8v*)(pa + k0 + 64);
            #pragma unroll
            for (int i = 0; i < 4; i++) B0[i] = *(const half8v*)(pb + i * 4096 + k0 + 64);
        }
        // MFMA on buf1
        #pragma unroll
        for (int cb = 0; cb < 4; cb++)
            acc[cb] = __builtin_amdgcn_mfma_f32_16x16x32_f16(A1, B1[cb], acc[cb], 0, 0, 0);
    }

    // C/D layout: col = h*64 + cb*16 + rlo, row = r0 + (lane>>4)*4 + i
    int rbase = r0 + ((lane >> 4) << 2);
    #pragma unroll
    for (int cb = 0; cb < 4; cb++) {
        #pragma unroll
        for (int i = 0; i < 4; i++)
            hp[(size_t)(rbase + i) * 256 + h * 64 + cb * 16 + rlo] = (half_t)acc[cb][i];
    }

    // fused a_s/a_d for this wave's head
    {
        float ps[4] = {0.f, 0.f, 0.f, 0.f};
        float pd[4] = {0.f, 0.f, 0.f, 0.f};
        #pragma unroll
        for (int cb = 0; cb < 4; cb++) {
            float av = asrc[h * 64 + cb * 16 + rlo];
            float dv = adst[h * 64 + cb * 16 + rlo];
            #pragma unroll
            for (int i = 0; i < 4; i++) {
                ps[i] += acc[cb][i] * av;
                pd[i] += acc[cb][i] * dv;
            }
        }
        #pragma unroll
        for (int mask = 1; mask <= 8; mask <<= 1) {
            #pragma unroll
            for (int i = 0; i < 4; i++) {
                ps[i] += __shfl_xor(ps[i], mask);
                pd[i] += __shfl_xor(pd[i], mask);
            }
        }
        if (rlo == 0) {
            #pragma unroll
            for (int i = 0; i < 4; i++) {
                as_out[(size_t)(rbase + i) * 4 + h] = ps[i];
                ad_out[(size_t)(rbase + i) * 4 + h] = pd[i];
            }
        }
    }
}

// ---------------- GAT aggregation: 8-edge-slot x half8 gather ----------------
__global__ __launch_bounds__(256) void gat_aggregate(
    const half_t* __restrict__ hp, const float* __restrict__ as_, const float* __restrict__ ad_,
    const int* __restrict__ row_ptr, const int* __restrict__ csr_src,
    const float* __restrict__ bias, half_t* __restrict__ hnext) {
    __shared__ float lds_e[4][LCAP];
    __shared__ int   lds_s[4][LCAP];
    int d = blockIdx.x;
    int h = threadIdx.x >> 6, lane = threadIdx.x & 63;
    int r0 = row_ptr[d], deg = row_ptr[d + 1] - r0;
    float adv = ad_[d * 4 + h];

    if (deg <= LCAP) {
        // phase A: lane-parallel exp + denom (fixed shift cancels in normalization)
        float ssum = 0.f;
        for (int i = lane; i < deg; i += 64) {
            int s = csr_src[r0 + i];
            float e = as_[s * 4 + h] + adv;
            e = e > 0.f ? e : NEG_SLOPE * e;
            float ex = __expf(e - ESHIFT);
            lds_s[h][i] = s;
            lds_e[h][i] = ex;
            ssum += ex;
        }
        #pragma unroll
        for (int o = 32; o; o >>= 1) ssum += __shfl_xor(ssum, o);
        float inv = 1.0f / ssum;

        // phase B: lane = (edge_slot es 0..7, chan-octet chq 0..7); 2-deep unroll -> 16 loads in flight
        int es = lane >> 3, chq = lane & 7;
        const half_t* hpb = hp + h * 64 + chq * 8;
        float c0 = 0.f, c1 = 0.f, c2 = 0.f, c3 = 0.f;
        float c4 = 0.f, c5 = 0.f, c6 = 0.f, c7 = 0.f;
        for (int i = 0; i < deg; i += 16) {
            #pragma unroll
            for (int u = 0; u < 2; u++) {
                int e = i + u * 8 + es;
                if (e < deg) {
                    int s = lds_s[h][e];
                    float a = lds_e[h][e];
                    half8v q = *(const half8v*)(hpb + (size_t)s * 256);
                    c0 += a * (float)q[0];
                    c1 += a * (float)q[1];
                    c2 += a * (float)q[2];
                    c3 += a * (float)q[3];
                    c4 += a * (float)q[4];
                    c5 += a * (float)q[5];
                    c6 += a * (float)q[6];
                    c7 += a * (float)q[7];
                }
            }
        }
        // reduce across the 8 edge slots
        #pragma unroll
        for (int o = 8; o <= 32; o <<= 1) {
            c0 += __shfl_xor(c0, o); c1 += __shfl_xor(c1, o);
            c2 += __shfl_xor(c2, o); c3 += __shfl_xor(c3, o);
            c4 += __shfl_xor(c4, o); c5 += __shfl_xor(c5, o);
            c6 += __shfl_xor(c6, o); c7 += __shfl_xor(c7, o);
        }
        if (es == 0) {
            float vv[8] = {c0, c1, c2, c3, c4, c5, c6, c7};
            half_t oh[8] __attribute__((aligned(16)));
            #pragma unroll
            for (int j = 0; j < 8; j++) {
                float v = vv[j] * inv + bias[h * 64 + chq * 8 + j];
                v = v > 0.f ? v : (__expf(v) - 1.0f);   // ELU
                oh[j] = (half_t)v;
            }
            *(half8v*)&hnext[(size_t)d * 256 + h * 64 + chq * 8] = *(half8v*)oh;
        }
    } else {
        // fallback: recompute path (deg > LCAP; not expected with this data)
        float ssum = 0.f;
        for (int i = lane; i < deg; i += 64) {
            int s = csr_src[r0 + i];
            float e = as_[s * 4 + h] + adv;
            e = e > 0.f ? e : NEG_SLOPE * e;
            ssum += __expf(e - ESHIFT);
        }
        #pragma unroll
        for (int o = 32; o; o >>= 1) ssum += __shfl_xor(ssum, o);
        float inv = 1.0f / ssum;
        float acc = 0.f;
        for (int i = 0; i < deg; i++) {
            int s = csr_src[r0 + i];
            float e = as_[s * 4 + h] + adv;
            e = e > 0.f ? e : NEG_SLOPE * e;
            acc += __expf(e - ESHIFT) * (float)hp[(size_t)s * 256 + h * 64 + lane];
        }
        float v = acc * inv + bias[h * 64 + lane];
        v = v > 0.f ? v : (__expf(v) - 1.0f);
        hnext[(size_t)d * 256 + h * 64 + lane] = (half_t)v;
    }
}

// ---------------- pooling + output head ----------------
__global__ __launch_bounds__(256) void col_sum_f16(const half_t* __restrict__ hin,
                                                   float* __restrict__ g, int N, int rows_per_blk) {
    int c = threadIdx.x;
    int r0 = blockIdx.x * rows_per_blk;
    int r1 = min(r0 + rows_per_blk, N);
    float acc = 0.f;
    for (int r = r0; r < r1; r++) acc += (float)hin[(size_t)r * D + c];
    atomicAdd(&g[c], acc);
}

__global__ __launch_bounds__(256) void final_kernel(const float* __restrict__ g,
                                                    const float* __restrict__ Wout,
                                                    const float* __restrict__ bout,
                                                    float* __restrict__ out, float invN) {
    int j = threadIdx.x;
    float acc = 0.f;
    for (int i = 0; i < D; i++) acc += g[i] * Wout[i * D + j];
    out[j] = acc * invN + bout[j];
}

extern "C" void kernel_launch(void* const* d_in, const int* in_sizes, int n_in,
                              void* d_out, int out_size, void* d_ws, size_t ws_size,
                              hipStream_t stream) {
    const float* x       = (const float*)d_in[0];
    const int*   ei      = (const int*)d_in[1];
    const float* Ws      = (const float*)d_in[2];
    const float* att_src = (const float*)d_in[3];
    const float* att_dst = (const float*)d_in[4];
    const float* biases  = (const float*)d_in[5];
    const float* Wout    = (const float*)d_in[6];
    const float* bout    = (const float*)d_in[7];
    float* out = (float*)d_out;

    int N = in_sizes[0] / D;          // 20000
    int E = in_sizes[1] / 2;          // 320000
    int L = in_sizes[2] / (D * D);    // 4
    int Etot = E + N;
    int Npad = (N + 63) & ~63;        // 20032

    char* ws = (char*)d_ws;
    size_t off = 0;
    auto alloc = [&](size_t bytes) -> void* {
        void* p = ws + off;
        off = (off + bytes + 255) & ~(size_t)255;
        return p;
    };
    half_t* xf16   = (half_t*)alloc((size_t)Npad * D * 2);
    half_t* hp     = (half_t*)alloc((size_t)Npad * D * 2);
    float* a_s     = (float*)alloc((size_t)Npad * H * 4);
    float* a_d     = (float*)alloc((size_t)Npad * H * 4);
    half_t* wt     = (half_t*)alloc((size_t)L * D * D * 2);
    float* g       = (float*)alloc(D * 4);
    int*   counts  = (int*)alloc((size_t)N * 4);
    int*   row_ptr = (int*)alloc((size_t)(N + 1) * 4);
    int*   cursor  = (int*)alloc((size_t)N * 4);
    int*   csr_src = (int*)alloc((size_t)Etot * 4);
    if (off > ws_size) return;

    int thr = 256;

    // ---- conversions ----
    int n8 = N * D / 8;
    conv_x<<<(n8 + thr - 1) / thr, thr, 0, stream>>>(x, xf16, n8);
    int wtot = L * D * D;
    conv_w<<<(wtot + thr - 1) / thr, thr, 0, stream>>>(Ws, wt, wtot);

    // ---- CSR build ----
    hipMemsetAsync(counts, 0, (size_t)N * 4, stream);
    count_kernel<<<(Etot + thr - 1) / thr, thr, 0, stream>>>(ei, E, N, counts);
    prefix_scan<<<1, 1024, 0, stream>>>(counts, row_ptr, cursor, N);
    scatter_kernel<<<(Etot + thr - 1) / thr, thr, 0, stream>>>(ei, E, N, cursor, csr_src);

    // ---- layers ----
    int gemm_blocks = Npad / 16;      // 1252
    for (int l = 0; l < L; l++) {
        gemm_f16<<<gemm_blocks, 256, 0, stream>>>(
            xf16, wt + (size_t)l * D * D,
            att_src + (size_t)l * H * C, att_dst + (size_t)l * H * C,
            hp, a_s, a_d);
        gat_aggregate<<<N, 256, 0, stream>>>(
            hp, a_s, a_d, row_ptr, csr_src, biases + (size_t)l * D, xf16);
    }

    // ---- pool + head ----
    hipMemsetAsync(g, 0, D * 4, stream);
    int rows_per_blk = 100;
    col_sum_f16<<<(N + rows_per_blk - 1) / rows_per_blk, thr, 0, stream>>>(xf16, g, N, rows_per_blk);
    final_kernel<<<1, thr, 0, stream>>>(g, Wout, bout, out, 1.0f / (float)N);
}

// Round 9
// 345.896 us; speedup vs baseline: 1.3495x; 1.1282x over previous
//
#include <hip/hip_runtime.h>
#include <hip/hip_bf16.h>

#define H 4
#define C 64
#define D 256
#define NEG_SLOPE 0.2f
#define LCAP 256
#define ESHIFT 8.0f

typedef _Float16 half_t;
typedef __attribute__((ext_vector_type(8))) _Float16 half8v;
typedef __attribute__((ext_vector_type(4))) float f32x4;

// Tiled ("fragment-linear") layout for MFMA operand matrices:
//   panel = 16 rows; within panel, half-offset(r,c) = (c>>5)*512 + ((c>>3)&3)*128 + r*8 + (c&7)
//   => a wave's fragment load for k-slab s is CONTIGUOUS: panel*4096 + s*512 + lane*8.

// ---------------- CSR build ----------------
__global__ void count_kernel(const int* __restrict__ ei, int E, int N, int* __restrict__ counts) {
    int i = blockIdx.x * blockDim.x + threadIdx.x;
    if (i >= E + N) return;
    int d = (i < E) ? ei[E + i] : (i - E);
    atomicAdd(&counts[d], 1);
}

// parallel scan, pass 1: block-local exclusive scan + block sums
__global__ __launch_bounds__(1024) void scan1(const int* __restrict__ counts,
                                              int* __restrict__ row_ptr,
                                              int* __restrict__ bsum, int N) {
    __shared__ int wsum[16];
    int tid = threadIdx.x, lane = tid & 63, wid = tid >> 6;
    int idx = blockIdx.x * 1024 + tid;
    int v = (idx < N) ? counts[idx] : 0;
    int val = v;
    #pragma unroll
    for (int o = 1; o < 64; o <<= 1) {
        int t = __shfl_up(val, o);
        if (lane >= o) val += t;
    }
    if (lane == 63) wsum[wid] = val;
    __syncthreads();
    int woff = 0;
    #pragma unroll
    for (int w = 0; w < 16; w++) woff += (w < wid) ? wsum[w] : 0;
    if (idx < N) row_ptr[idx] = woff + val - v;      // block-local exclusive
    if (tid == 1023) bsum[blockIdx.x] = woff + val;  // block total
}

// pass 2: single wave scans the <=64 block sums into exclusive offsets; writes row_ptr[N]
__global__ void scan2(int* __restrict__ bsum, int* __restrict__ row_ptr, int nb, int N) {
    int lane = threadIdx.x;
    int v = (lane < nb) ? bsum[lane] : 0;
    int val = v;
    #pragma unroll
    for (int o = 1; o < 64; o <<= 1) {
        int t = __shfl_up(val, o);
        if (lane >= o) val += t;
    }
    if (lane < nb) bsum[lane] = val - v;             // exclusive offset
    if (lane == 63) row_ptr[N] = val;                // grand total
}

// pass 3: add block offsets; produce cursor copy
__global__ __launch_bounds__(1024) void scan3(int* __restrict__ row_ptr,
                                              const int* __restrict__ bsum,
                                              int* __restrict__ cursor, int N) {
    int idx = blockIdx.x * 1024 + threadIdx.x;
    if (idx >= N) return;
    int r = row_ptr[idx] + bsum[blockIdx.x];
    row_ptr[idx] = r;
    cursor[idx] = r;
}

__global__ void scatter_kernel(const int* __restrict__ ei, int E, int N,
                               int* __restrict__ cursor, int* __restrict__ csr_src) {
    int i = blockIdx.x * blockDim.x + threadIdx.x;
    if (i >= E + N) return;
    int s, d;
    if (i < E) { s = ei[i]; d = ei[E + i]; }
    else       { s = d = i - E; }
    int pos = atomicAdd(&cursor[d], 1);
    csr_src[pos] = s;
}

// ---------------- fp32 -> f16 tiled conversions ----------------
// thread t: row i = t>>5, col-octet o = t&31; read 32B, write 16B tiled
__global__ void conv_x(const float* __restrict__ in, half_t* __restrict__ xt, int total) {
    int t = blockIdx.x * blockDim.x + threadIdx.x;
    if (t >= total) return;
    int i = t >> 5, o = t & 31;
    const float* src = in + (size_t)i * 256 + o * 8;
    float4 v0 = *(const float4*)src;
    float4 v1 = *(const float4*)(src + 4);
    half_t q[8] __attribute__((aligned(16)));
    q[0] = (half_t)v0.x; q[1] = (half_t)v0.y; q[2] = (half_t)v0.z; q[3] = (half_t)v0.w;
    q[4] = (half_t)v1.x; q[5] = (half_t)v1.y; q[6] = (half_t)v1.z; q[7] = (half_t)v1.w;
    size_t dst = (size_t)(i >> 4) * 4096 + (o >> 2) * 512 + (o & 3) * 128 + (i & 15) * 8;
    *(half8v*)(xt + dst) = *(half8v*)q;
}

// W[l][k][col] -> fragment-linear chunks: wt[((l*4+h)*4+cb)*8+s)*512 + L*8 + j]
// where chunk (l,h,cb,s) lane L covers col = h*64+cb*16+(L&15), k = 32s+(L>>4)*8+j
__global__ void conv_w(const float* __restrict__ W, half_t* __restrict__ wt, int total) {
    int idx = blockIdx.x * blockDim.x + threadIdx.x;
    if (idx >= total) return;   // total = L*4*4*8*64
    int Lr = idx & 63;
    int s  = (idx >> 6) & 7;
    int cb = (idx >> 9) & 3;
    int h  = (idx >> 11) & 3;
    int l  = idx >> 13;
    int col = h * 64 + cb * 16 + (Lr & 15);
    int k0  = 32 * s + (Lr >> 4) * 8;
    half_t q[8] __attribute__((aligned(16)));
    #pragma unroll
    for (int j = 0; j < 8; j++)
        q[j] = (half_t)W[(size_t)l * 65536 + (size_t)(k0 + j) * 256 + col];
    *(half8v*)(wt + (size_t)idx * 8) = *(half8v*)q;
}

// ---------------- f16 MFMA GEMM + fused attention scores ----------------
// grid Npad/16 (=1252); block = 16 rows x 256 cols; wave = head = 16 rows x 64 cols.
// ALL loads are contiguous 1KB wave transactions (fragment-linear layout).
__global__ __launch_bounds__(256) void gemm_f16(
    const half_t* __restrict__ At, const half_t* __restrict__ Wt,
    const float* __restrict__ asrc, const float* __restrict__ adst,
    half_t* __restrict__ hp, float* __restrict__ as_out, float* __restrict__ ad_out) {
    int wv = threadIdx.x >> 6, lane = threadIdx.x & 63;
    int h = wv;                    // wave == head
    int r0 = blockIdx.x * 16;
    int rlo = lane & 15;
    const half_t* pa = At + (size_t)blockIdx.x * 4096 + lane * 8;   // + s*512
    const half_t* pb = Wt + (size_t)h * 16384 + lane * 8;           // + cb*4096 + s*512

    f32x4 acc[4];
    #pragma unroll
    for (int cb = 0; cb < 4; cb++) acc[cb] = (f32x4){0.f, 0.f, 0.f, 0.f};

    half8v A0, B0[4], A1, B1[4];

    A0 = *(const half8v*)(pa);
    #pragma unroll
    for (int i = 0; i < 4; i++) B0[i] = *(const half8v*)(pb + i * 4096);

    #pragma unroll
    for (int s = 0; s < 8; s += 2) {
        A1 = *(const half8v*)(pa + (s + 1) * 512);
        #pragma unroll
        for (int i = 0; i < 4; i++) B1[i] = *(const half8v*)(pb + i * 4096 + (s + 1) * 512);
        #pragma unroll
        for (int cb = 0; cb < 4; cb++)
            acc[cb] = __builtin_amdgcn_mfma_f32_16x16x32_f16(A0, B0[cb], acc[cb], 0, 0, 0);
        if (s < 6) {
            A0 = *(const half8v*)(pa + (s + 2) * 512);
            #pragma unroll
            for (int i = 0; i < 4; i++) B0[i] = *(const half8v*)(pb + i * 4096 + (s + 2) * 512);
        }
        #pragma unroll
        for (int cb = 0; cb < 4; cb++)
            acc[cb] = __builtin_amdgcn_mfma_f32_16x16x32_f16(A1, B1[cb], acc[cb], 0, 0, 0);
    }

    // hp (row-major, for the gather): col = h*64 + cb*16 + rlo, row = r0 + (lane>>4)*4 + i
    int rbase = r0 + ((lane >> 4) << 2);
    #pragma unroll
    for (int cb = 0; cb < 4; cb++) {
        #pragma unroll
        for (int i = 0; i < 4; i++)
            hp[(size_t)(rbase + i) * 256 + h * 64 + cb * 16 + rlo] = (half_t)acc[cb][i];
    }

    // fused a_s/a_d for this wave's head
    {
        float ps[4] = {0.f, 0.f, 0.f, 0.f};
        float pd[4] = {0.f, 0.f, 0.f, 0.f};
        #pragma unroll
        for (int cb = 0; cb < 4; cb++) {
            float av = asrc[h * 64 + cb * 16 + rlo];
            float dv = adst[h * 64 + cb * 16 + rlo];
            #pragma unroll
            for (int i = 0; i < 4; i++) {
                ps[i] += acc[cb][i] * av;
                pd[i] += acc[cb][i] * dv;
            }
        }
        #pragma unroll
        for (int mask = 1; mask <= 8; mask <<= 1) {
            #pragma unroll
            for (int i = 0; i < 4; i++) {
                ps[i] += __shfl_xor(ps[i], mask);
                pd[i] += __shfl_xor(pd[i], mask);
            }
        }
        if (rlo == 0) {
            #pragma unroll
            for (int i = 0; i < 4; i++) {
                as_out[(size_t)(rbase + i) * 4 + h] = ps[i];
                ad_out[(size_t)(rbase + i) * 4 + h] = pd[i];
            }
        }
    }
}

// ---------------- GAT aggregation: 8-edge-slot x half8 gather; writes h in tiled layout ----------------
__global__ __launch_bounds__(256) void gat_aggregate(
    const half_t* __restrict__ hp, const float* __restrict__ as_, const float* __restrict__ ad_,
    const int* __restrict__ row_ptr, const int* __restrict__ csr_src,
    const float* __restrict__ bias, half_t* __restrict__ hnext) {
    __shared__ float lds_e[4][LCAP];
    __shared__ int   lds_s[4][LCAP];
    int d = blockIdx.x;
    int h = threadIdx.x >> 6, lane = threadIdx.x & 63;
    int r0 = row_ptr[d], deg = row_ptr[d + 1] - r0;
    float adv = ad_[d * 4 + h];

    if (deg <= LCAP) {
        float ssum = 0.f;
        for (int i = lane; i < deg; i += 64) {
            int s = csr_src[r0 + i];
            float e = as_[s * 4 + h] + adv;
            e = e > 0.f ? e : NEG_SLOPE * e;
            float ex = __expf(e - ESHIFT);
            lds_s[h][i] = s;
            lds_e[h][i] = ex;
            ssum += ex;
        }
        #pragma unroll
        for (int o = 32; o; o >>= 1) ssum += __shfl_xor(ssum, o);
        float inv = 1.0f / ssum;

        int es = lane >> 3, chq = lane & 7;
        const half_t* hpb = hp + h * 64 + chq * 8;
        float c0 = 0.f, c1 = 0.f, c2 = 0.f, c3 = 0.f;
        float c4 = 0.f, c5 = 0.f, c6 = 0.f, c7 = 0.f;
        for (int i = 0; i < deg; i += 16) {
            #pragma unroll
            for (int u = 0; u < 2; u++) {
                int e = i + u * 8 + es;
                if (e < deg) {
                    int s = lds_s[h][e];
                    float a = lds_e[h][e];
                    half8v q = *(const half8v*)(hpb + (size_t)s * 256);
                    c0 += a * (float)q[0];
                    c1 += a * (float)q[1];
                    c2 += a * (float)q[2];
                    c3 += a * (float)q[3];
                    c4 += a * (float)q[4];
                    c5 += a * (float)q[5];
                    c6 += a * (float)q[6];
                    c7 += a * (float)q[7];
                }
            }
        }
        #pragma unroll
        for (int o = 8; o <= 32; o <<= 1) {
            c0 += __shfl_xor(c0, o); c1 += __shfl_xor(c1, o);
            c2 += __shfl_xor(c2, o); c3 += __shfl_xor(c3, o);
            c4 += __shfl_xor(c4, o); c5 += __shfl_xor(c5, o);
            c6 += __shfl_xor(c6, o); c7 += __shfl_xor(c7, o);
        }
        if (es == 0) {
            float vv[8] = {c0, c1, c2, c3, c4, c5, c6, c7};
            half_t oh[8] __attribute__((aligned(16)));
            #pragma unroll
            for (int j = 0; j < 8; j++) {
                float v = vv[j] * inv + bias[h * 64 + chq * 8 + j];
                v = v > 0.f ? v : (__expf(v) - 1.0f);   // ELU
                oh[j] = (half_t)v;
            }
            int o = h * 8 + chq;   // col-octet
            size_t dst = (size_t)(d >> 4) * 4096 + (o >> 2) * 512 + (o & 3) * 128 + (d & 15) * 8;
            *(half8v*)(hnext + dst) = *(half8v*)oh;
        }
    } else {
        // fallback (deg > LCAP): recompute path, scalar tiled writes
        float ssum = 0.f;
        for (int i = lane; i < deg; i += 64) {
            int s = csr_src[r0 + i];
            float e = as_[s * 4 + h] + adv;
            e = e > 0.f ? e : NEG_SLOPE * e;
            ssum += __expf(e - ESHIFT);
        }
        #pragma unroll
        for (int o = 32; o; o >>= 1) ssum += __shfl_xor(ssum, o);
        float inv = 1.0f / ssum;
        float acc = 0.f;
        for (int i = 0; i < deg; i++) {
            int s = csr_src[r0 + i];
            float e = as_[s * 4 + h] + adv;
            e = e > 0.f ? e : NEG_SLOPE * e;
            acc += __expf(e - ESHIFT) * (float)hp[(size_t)s * 256 + h * 64 + lane];
        }
        float v = acc * inv + bias[h * 64 + lane];
        v = v > 0.f ? v : (__expf(v) - 1.0f);
        int c = h * 64 + lane;
        size_t dst = (size_t)(d >> 4) * 4096 + (c >> 5) * 512 + ((c >> 3) & 3) * 128 + (d & 15) * 8 + (c & 7);
        hnext[dst] = (half_t)v;
    }
}

// ---------------- pooling + output head (tiled input, partial sums, no atomics) ----------------
__global__ __launch_bounds__(256) void col_sum_f16(const half_t* __restrict__ hin,
                                                   float* __restrict__ partial, int N, int rows_per_blk) {
    int c = threadIdx.x;
    int r0 = blockIdx.x * rows_per_blk;
    int r1 = min(r0 + rows_per_blk, N);
    int coff = (c >> 5) * 512 + ((c >> 3) & 3) * 128 + (c & 7);
    float acc = 0.f;
    for (int r = r0; r < r1; r++)
        acc += (float)hin[(size_t)(r >> 4) * 4096 + coff + (r & 15) * 8];
    partial[(size_t)blockIdx.x * 256 + c] = acc;
}

__global__ __launch_bounds__(256) void final_kernel(const float* __restrict__ partial,
                                                    const float* __restrict__ Wout,
                                                    const float* __restrict__ bout,
                                                    float* __restrict__ out, float invN, int nb) {
    __shared__ float gl[256];
    int j = threadIdx.x;
    float s = 0.f;
    for (int b = 0; b < nb; b++) s += partial[(size_t)b * 256 + j];
    gl[j] = s;
    __syncthreads();
    float acc = 0.f;
    for (int i = 0; i < 256; i++) acc += gl[i] * Wout[i * 256 + j];
    out[j] = acc * invN + bout[j];
}

extern "C" void kernel_launch(void* const* d_in, const int* in_sizes, int n_in,
                              void* d_out, int out_size, void* d_ws, size_t ws_size,
                              hipStream_t stream) {
    const float* x       = (const float*)d_in[0];
    const int*   ei      = (const int*)d_in[1];
    const float* Ws      = (const float*)d_in[2];
    const float* att_src = (const float*)d_in[3];
    const float* att_dst = (const float*)d_in[4];
    const float* biases  = (const float*)d_in[5];
    const float* Wout    = (const float*)d_in[6];
    const float* bout    = (const float*)d_in[7];
    float* out = (float*)d_out;

    int N = in_sizes[0] / D;          // 20000
    int E = in_sizes[1] / 2;          // 320000
    int L = in_sizes[2] / (D * D);    // 4
    int Etot = E + N;
    int Npad = (N + 63) & ~63;        // 20032 (1252 panels)

    char* ws = (char*)d_ws;
    size_t off = 0;
    auto alloc = [&](size_t bytes) -> void* {
        void* p = ws + off;
        off = (off + bytes + 255) & ~(size_t)255;
        return p;
    };
    half_t* xt     = (half_t*)alloc((size_t)Npad * D * 2);   // tiled A / h
    half_t* hp     = (half_t*)alloc((size_t)Npad * D * 2);   // row-major hp
    float* a_s     = (float*)alloc((size_t)Npad * H * 4);
    float* a_d     = (float*)alloc((size_t)Npad * H * 4);
    half_t* wt     = (half_t*)alloc((size_t)L * D * D * 2);  // fragment-linear W
    int*   counts  = (int*)alloc((size_t)N * 4);
    int*   row_ptr = (int*)alloc((size_t)(N + 1) * 4);
    int*   cursor  = (int*)alloc((size_t)N * 4);
    int*   bsum    = (int*)alloc(64 * 4);
    int*   csr_src = (int*)alloc((size_t)Etot * 4);
    int rows_per_blk = 254;
    int nb_pool = (N + rows_per_blk - 1) / rows_per_blk;     // 79
    float* partial = (float*)alloc((size_t)nb_pool * 256 * 4);
    if (off > ws_size) return;

    int thr = 256;

    // ---- conversions (tiled) ----
    int xtot = N * 32;
    conv_x<<<(xtot + thr - 1) / thr, thr, 0, stream>>>(x, xt, xtot);
    int wtot = L * 4 * 4 * 8 * 64;
    conv_w<<<(wtot + thr - 1) / thr, thr, 0, stream>>>(Ws, wt, wtot);

    // ---- CSR build (parallel scan) ----
    hipMemsetAsync(counts, 0, (size_t)N * 4, stream);
    count_kernel<<<(Etot + thr - 1) / thr, thr, 0, stream>>>(ei, E, N, counts);
    int nb_scan = (N + 1023) / 1024;  // 20
    scan1<<<nb_scan, 1024, 0, stream>>>(counts, row_ptr, bsum, N);
    scan2<<<1, 64, 0, stream>>>(bsum, row_ptr, nb_scan, N);
    scan3<<<nb_scan, 1024, 0, stream>>>(row_ptr, bsum, cursor, N);
    scatter_kernel<<<(Etot + thr - 1) / thr, thr, 0, stream>>>(ei, E, N, cursor, csr_src);

    // ---- layers ----
    int gemm_blocks = Npad / 16;      // 1252
    for (int l = 0; l < L; l++) {
        gemm_f16<<<gemm_blocks, 256, 0, stream>>>(
            xt, wt + (size_t)l * D * D,
            att_src + (size_t)l * H * C, att_dst + (size_t)l * H * C,
            hp, a_s, a_d);
        gat_aggregate<<<N, 256, 0, stream>>>(
            hp, a_s, a_d, row_ptr, csr_src, biases + (size_t)l * D, xt);
    }

    // ---- pool + head ----
    col_sum_f16<<<nb_pool, thr, 0, stream>>>(xt, partial, N, rows_per_blk);
    final_kernel<<<1, thr, 0, stream>>>(partial, Wout, bout, out, 1.0f / (float)N, nb_pool);
}

// Round 10
// 335.230 us; speedup vs baseline: 1.3925x; 1.0318x over previous
//
#include <hip/hip_runtime.h>
#include <hip/hip_bf16.h>

#define H 4
#define C 64
#define D 256
#define NEG_SLOPE 0.2f
#define LCAP 256
#define ESHIFT 8.0f

typedef _Float16 half_t;
typedef __attribute__((ext_vector_type(8))) _Float16 half8v;
typedef __attribute__((ext_vector_type(4))) float f32x4;

// Tiled ("fragment-linear") layout for MFMA operand matrices:
//   panel = 16 rows; within panel, half-offset(r,c) = (c>>5)*512 + ((c>>3)&3)*128 + r*8 + (c&7)
//   => a wave's fragment load for k-slab s is CONTIGUOUS: panel*4096 + s*512 + lane*8.
// hp / a_s / a_d are HEAD-MAJOR: hp[h][n][64], a_s[h][n] -- so the aggregation's
// per-head working set (2.56MB) fits one XCD's 4MiB L2 (head-phased grid).

// ---------------- CSR build ----------------
__global__ void count_kernel(const int* __restrict__ ei, int E, int N, int* __restrict__ counts) {
    int i = blockIdx.x * blockDim.x + threadIdx.x;
    if (i >= E + N) return;
    int d = (i < E) ? ei[E + i] : (i - E);
    atomicAdd(&counts[d], 1);
}

__global__ __launch_bounds__(1024) void scan1(const int* __restrict__ counts,
                                              int* __restrict__ row_ptr,
                                              int* __restrict__ bsum, int N) {
    __shared__ int wsum[16];
    int tid = threadIdx.x, lane = tid & 63, wid = tid >> 6;
    int idx = blockIdx.x * 1024 + tid;
    int v = (idx < N) ? counts[idx] : 0;
    int val = v;
    #pragma unroll
    for (int o = 1; o < 64; o <<= 1) {
        int t = __shfl_up(val, o);
        if (lane >= o) val += t;
    }
    if (lane == 63) wsum[wid] = val;
    __syncthreads();
    int woff = 0;
    #pragma unroll
    for (int w = 0; w < 16; w++) woff += (w < wid) ? wsum[w] : 0;
    if (idx < N) row_ptr[idx] = woff + val - v;
    if (tid == 1023) bsum[blockIdx.x] = woff + val;
}

__global__ void scan2(int* __restrict__ bsum, int* __restrict__ row_ptr, int nb, int N) {
    int lane = threadIdx.x;
    int v = (lane < nb) ? bsum[lane] : 0;
    int val = v;
    #pragma unroll
    for (int o = 1; o < 64; o <<= 1) {
        int t = __shfl_up(val, o);
        if (lane >= o) val += t;
    }
    if (lane < nb) bsum[lane] = val - v;
    if (lane == 63) row_ptr[N] = val;
}

__global__ __launch_bounds__(1024) void scan3(int* __restrict__ row_ptr,
                                              const int* __restrict__ bsum,
                                              int* __restrict__ cursor, int N) {
    int idx = blockIdx.x * 1024 + threadIdx.x;
    if (idx >= N) return;
    int r = row_ptr[idx] + bsum[blockIdx.x];
    row_ptr[idx] = r;
    cursor[idx] = r;
}

__global__ void scatter_kernel(const int* __restrict__ ei, int E, int N,
                               int* __restrict__ cursor, int* __restrict__ csr_src) {
    int i = blockIdx.x * blockDim.x + threadIdx.x;
    if (i >= E + N) return;
    int s, d;
    if (i < E) { s = ei[i]; d = ei[E + i]; }
    else       { s = d = i - E; }
    int pos = atomicAdd(&cursor[d], 1);
    csr_src[pos] = s;
}

// ---------------- fp32 -> f16 tiled conversions ----------------
__global__ void conv_x(const float* __restrict__ in, half_t* __restrict__ xt, int total) {
    int t = blockIdx.x * blockDim.x + threadIdx.x;
    if (t >= total) return;
    int i = t >> 5, o = t & 31;
    const float* src = in + (size_t)i * 256 + o * 8;
    float4 v0 = *(const float4*)src;
    float4 v1 = *(const float4*)(src + 4);
    half_t q[8] __attribute__((aligned(16)));
    q[0] = (half_t)v0.x; q[1] = (half_t)v0.y; q[2] = (half_t)v0.z; q[3] = (half_t)v0.w;
    q[4] = (half_t)v1.x; q[5] = (half_t)v1.y; q[6] = (half_t)v1.z; q[7] = (half_t)v1.w;
    size_t dst = (size_t)(i >> 4) * 4096 + (o >> 2) * 512 + (o & 3) * 128 + (i & 15) * 8;
    *(half8v*)(xt + dst) = *(half8v*)q;
}

__global__ void conv_w(const float* __restrict__ W, half_t* __restrict__ wt, int total) {
    int idx = blockIdx.x * blockDim.x + threadIdx.x;
    if (idx >= total) return;   // total = L*4*4*8*64
    int Lr = idx & 63;
    int s  = (idx >> 6) & 7;
    int cb = (idx >> 9) & 3;
    int h  = (idx >> 11) & 3;
    int l  = idx >> 13;
    int col = h * 64 + cb * 16 + (Lr & 15);
    int k0  = 32 * s + (Lr >> 4) * 8;
    half_t q[8] __attribute__((aligned(16)));
    #pragma unroll
    for (int j = 0; j < 8; j++)
        q[j] = (half_t)W[(size_t)l * 65536 + (size_t)(k0 + j) * 256 + col];
    *(half8v*)(wt + (size_t)idx * 8) = *(half8v*)q;
}

// ---------------- f16 MFMA GEMM + fused attention scores ----------------
// grid Npad/16 (=1252); block = 16 rows x 256 cols; wave = head = 16 rows x 64 cols.
__global__ __launch_bounds__(256) void gemm_f16(
    const half_t* __restrict__ At, const half_t* __restrict__ Wt,
    const float* __restrict__ asrc, const float* __restrict__ adst,
    half_t* __restrict__ hp, float* __restrict__ as_out, float* __restrict__ ad_out,
    int Npad) {
    int wv = threadIdx.x >> 6, lane = threadIdx.x & 63;
    int h = wv;                    // wave == head
    int r0 = blockIdx.x * 16;
    int rlo = lane & 15;
    const half_t* pa = At + (size_t)blockIdx.x * 4096 + lane * 8;   // + s*512
    const half_t* pb = Wt + (size_t)h * 16384 + lane * 8;           // + cb*4096 + s*512

    f32x4 acc[4];
    #pragma unroll
    for (int cb = 0; cb < 4; cb++) acc[cb] = (f32x4){0.f, 0.f, 0.f, 0.f};

    half8v A0, B0[4], A1, B1[4];

    A0 = *(const half8v*)(pa);
    #pragma unroll
    for (int i = 0; i < 4; i++) B0[i] = *(const half8v*)(pb + i * 4096);

    #pragma unroll
    for (int s = 0; s < 8; s += 2) {
        A1 = *(const half8v*)(pa + (s + 1) * 512);
        #pragma unroll
        for (int i = 0; i < 4; i++) B1[i] = *(const half8v*)(pb + i * 4096 + (s + 1) * 512);
        #pragma unroll
        for (int cb = 0; cb < 4; cb++)
            acc[cb] = __builtin_amdgcn_mfma_f32_16x16x32_f16(A0, B0[cb], acc[cb], 0, 0, 0);
        if (s < 6) {
            A0 = *(const half8v*)(pa + (s + 2) * 512);
            #pragma unroll
            for (int i = 0; i < 4; i++) B0[i] = *(const half8v*)(pb + i * 4096 + (s + 2) * 512);
        }
        #pragma unroll
        for (int cb = 0; cb < 4; cb++)
            acc[cb] = __builtin_amdgcn_mfma_f32_16x16x32_f16(A1, B1[cb], acc[cb], 0, 0, 0);
    }

    // hp HEAD-MAJOR: hp[h][row][ch]: ch = cb*16 + rlo, row = r0 + (lane>>4)*4 + i
    int rbase = r0 + ((lane >> 4) << 2);
    half_t* hph = hp + (size_t)h * Npad * 64;
    #pragma unroll
    for (int cb = 0; cb < 4; cb++) {
        #pragma unroll
        for (int i = 0; i < 4; i++)
            hph[(size_t)(rbase + i) * 64 + cb * 16 + rlo] = (half_t)acc[cb][i];
    }

    // fused a_s/a_d for this wave's head (head-major outputs)
    {
        float ps[4] = {0.f, 0.f, 0.f, 0.f};
        float pd[4] = {0.f, 0.f, 0.f, 0.f};
        #pragma unroll
        for (int cb = 0; cb < 4; cb++) {
            float av = asrc[h * 64 + cb * 16 + rlo];
            float dv = adst[h * 64 + cb * 16 + rlo];
            #pragma unroll
            for (int i = 0; i < 4; i++) {
                ps[i] += acc[cb][i] * av;
                pd[i] += acc[cb][i] * dv;
            }
        }
        #pragma unroll
        for (int mask = 1; mask <= 8; mask <<= 1) {
            #pragma unroll
            for (int i = 0; i < 4; i++) {
                ps[i] += __shfl_xor(ps[i], mask);
                pd[i] += __shfl_xor(pd[i], mask);
            }
        }
        if (rlo == 0) {
            #pragma unroll
            for (int i = 0; i < 4; i++) {
                as_out[(size_t)h * Npad + rbase + i] = ps[i];
                ad_out[(size_t)h * Npad + rbase + i] = pd[i];
            }
        }
    }
}

// ---------------- GAT aggregation: head-phased grid, one wave per (node, head) ----------------
// grid = 4 heads x ngroups (4 nodes each); blocks of one head are contiguous in dispatch
// order, so each XCD's L2 holds ~one head's hp slab (2.56MB < 4MiB) -> gather is L2-hit.
__global__ __launch_bounds__(256) void gat_aggregate(
    const half_t* __restrict__ hp, const float* __restrict__ as_, const float* __restrict__ ad_,
    const int* __restrict__ row_ptr, const int* __restrict__ csr_src,
    const float* __restrict__ bias, half_t* __restrict__ hnext, int N, int Npad, int ngroups) {
    __shared__ float lds_e[4][LCAP];
    __shared__ int   lds_s[4][LCAP];
    int wv = threadIdx.x >> 6, lane = threadIdx.x & 63;
    int h = blockIdx.x / ngroups;
    int d = (blockIdx.x % ngroups) * 4 + wv;
    if (d >= N) return;
    int r0 = row_ptr[d], deg = row_ptr[d + 1] - r0;
    const float* ash = as_ + (size_t)h * Npad;
    float adv = ad_[(size_t)h * Npad + d];
    const half_t* hph = hp + (size_t)h * Npad * 64;

    if (deg <= LCAP) {
        // phase A: lane-parallel exp + denom (fixed shift cancels in normalization)
        float ssum = 0.f;
        for (int i = lane; i < deg; i += 64) {
            int s = csr_src[r0 + i];
            float e = ash[s] + adv;
            e = e > 0.f ? e : NEG_SLOPE * e;
            float ex = __expf(e - ESHIFT);
            lds_s[wv][i] = s;
            lds_e[wv][i] = ex;
            ssum += ex;
        }
        #pragma unroll
        for (int o = 32; o; o >>= 1) ssum += __shfl_xor(ssum, o);
        float inv = 1.0f / ssum;

        // phase B: lane = (edge_slot es 0..7, chan-octet chq 0..7); branch-free guards
        int es = lane >> 3, chq = lane & 7;
        const half_t* hpb = hph + chq * 8;
        float c0 = 0.f, c1 = 0.f, c2 = 0.f, c3 = 0.f;
        float c4 = 0.f, c5 = 0.f, c6 = 0.f, c7 = 0.f;
        for (int i = 0; i < deg; i += 16) {
            #pragma unroll
            for (int u = 0; u < 2; u++) {
                int e = i + u * 8 + es;
                int ec = e < deg ? e : 0;
                float a = e < deg ? lds_e[wv][ec] : 0.f;
                int s = lds_s[wv][ec];
                half8v q = *(const half8v*)(hpb + (size_t)s * 64);
                c0 += a * (float)q[0];
                c1 += a * (float)q[1];
                c2 += a * (float)q[2];
                c3 += a * (float)q[3];
                c4 += a * (float)q[4];
                c5 += a * (float)q[5];
                c6 += a * (float)q[6];
                c7 += a * (float)q[7];
            }
        }
        #pragma unroll
        for (int o = 8; o <= 32; o <<= 1) {
            c0 += __shfl_xor(c0, o); c1 += __shfl_xor(c1, o);
            c2 += __shfl_xor(c2, o); c3 += __shfl_xor(c3, o);
            c4 += __shfl_xor(c4, o); c5 += __shfl_xor(c5, o);
            c6 += __shfl_xor(c6, o); c7 += __shfl_xor(c7, o);
        }
        if (es == 0) {
            float vv[8] = {c0, c1, c2, c3, c4, c5, c6, c7};
            half_t oh[8] __attribute__((aligned(16)));
            #pragma unroll
            for (int j = 0; j < 8; j++) {
                float v = vv[j] * inv + bias[h * 64 + chq * 8 + j];
                v = v > 0.f ? v : (__expf(v) - 1.0f);   // ELU
                oh[j] = (half_t)v;
            }
            int o = h * 8 + chq;   // col-octet in tiled layout
            size_t dst = (size_t)(d >> 4) * 4096 + (o >> 2) * 512 + (o & 3) * 128 + (d & 15) * 8;
            *(half8v*)(hnext + dst) = *(half8v*)oh;
        }
    } else {
        // fallback (deg > LCAP): recompute path
        float ssum = 0.f;
        for (int i = lane; i < deg; i += 64) {
            int s = csr_src[r0 + i];
            float e = ash[s] + adv;
            e = e > 0.f ? e : NEG_SLOPE * e;
            ssum += __expf(e - ESHIFT);
        }
        #pragma unroll
        for (int o = 32; o; o >>= 1) ssum += __shfl_xor(ssum, o);
        float inv = 1.0f / ssum;
        float acc = 0.f;
        for (int i = 0; i < deg; i++) {
            int s = csr_src[r0 + i];
            float e = ash[s] + adv;
            e = e > 0.f ? e : NEG_SLOPE * e;
            acc += __expf(e - ESHIFT) * (float)hph[(size_t)s * 64 + lane];
        }
        float v = acc * inv + bias[h * 64 + lane];
        v = v > 0.f ? v : (__expf(v) - 1.0f);
        int c = h * 64 + lane;
        size_t dst = (size_t)(d >> 4) * 4096 + (c >> 5) * 512 + ((c >> 3) & 3) * 128 + (d & 15) * 8 + (c & 7);
        hnext[dst] = (half_t)v;
    }
}

// ---------------- pooling + output head ----------------
__global__ __launch_bounds__(256) void col_sum_f16(const half_t* __restrict__ hin,
                                                   float* __restrict__ partial, int N, int rows_per_blk) {
    int c = threadIdx.x;
    int r0 = blockIdx.x * rows_per_blk;
    int r1 = min(r0 + rows_per_blk, N);
    int coff = (c >> 5) * 512 + ((c >> 3) & 3) * 128 + (c & 7);
    float acc = 0.f;
    for (int r = r0; r < r1; r++)
        acc += (float)hin[(size_t)(r >> 4) * 4096 + coff + (r & 15) * 8];
    partial[(size_t)blockIdx.x * 256 + c] = acc;
}

__global__ __launch_bounds__(256) void final_kernel(const float* __restrict__ partial,
                                                    const float* __restrict__ Wout,
                                                    const float* __restrict__ bout,
                                                    float* __restrict__ out, float invN, int nb) {
    __shared__ float gl[256];
    int j = threadIdx.x;
    float s = 0.f;
    for (int b = 0; b < nb; b++) s += partial[(size_t)b * 256 + j];
    gl[j] = s;
    __syncthreads();
    float acc = 0.f;
    for (int i = 0; i < 256; i++) acc += gl[i] * Wout[i * 256 + j];
    out[j] = acc * invN + bout[j];
}

extern "C" void kernel_launch(void* const* d_in, const int* in_sizes, int n_in,
                              void* d_out, int out_size, void* d_ws, size_t ws_size,
                              hipStream_t stream) {
    const float* x       = (const float*)d_in[0];
    const int*   ei      = (const int*)d_in[1];
    const float* Ws      = (const float*)d_in[2];
    const float* att_src = (const float*)d_in[3];
    const float* att_dst = (const float*)d_in[4];
    const float* biases  = (const float*)d_in[5];
    const float* Wout    = (const float*)d_in[6];
    const float* bout    = (const float*)d_in[7];
    float* out = (float*)d_out;

    int N = in_sizes[0] / D;          // 20000
    int E = in_sizes[1] / 2;          // 320000
    int L = in_sizes[2] / (D * D);    // 4
    int Etot = E + N;
    int Npad = (N + 63) & ~63;        // 20032 (1252 panels)

    char* ws = (char*)d_ws;
    size_t off = 0;
    auto alloc = [&](size_t bytes) -> void* {
        void* p = ws + off;
        off = (off + bytes + 255) & ~(size_t)255;
        return p;
    };
    half_t* xt     = (half_t*)alloc((size_t)Npad * D * 2);   // tiled A / h
    half_t* hp     = (half_t*)alloc((size_t)Npad * D * 2);   // head-major hp
    float* a_s     = (float*)alloc((size_t)Npad * H * 4);    // head-major
    float* a_d     = (float*)alloc((size_t)Npad * H * 4);
    half_t* wt     = (half_t*)alloc((size_t)L * D * D * 2);  // fragment-linear W
    int*   counts  = (int*)alloc((size_t)N * 4);
    int*   row_ptr = (int*)alloc((size_t)(N + 1) * 4);
    int*   cursor  = (int*)alloc((size_t)N * 4);
    int*   bsum    = (int*)alloc(64 * 4);
    int*   csr_src = (int*)alloc((size_t)Etot * 4);
    int rows_per_blk = 254;
    int nb_pool = (N + rows_per_blk - 1) / rows_per_blk;     // 79
    float* partial = (float*)alloc((size_t)nb_pool * 256 * 4);
    if (off > ws_size) return;

    int thr = 256;

    // ---- conversions (tiled) ----
    int xtot = N * 32;
    conv_x<<<(xtot + thr - 1) / thr, thr, 0, stream>>>(x, xt, xtot);
    int wtot = L * 4 * 4 * 8 * 64;
    conv_w<<<(wtot + thr - 1) / thr, thr, 0, stream>>>(Ws, wt, wtot);

    // ---- CSR build (parallel scan) ----
    hipMemsetAsync(counts, 0, (size_t)N * 4, stream);
    count_kernel<<<(Etot + thr - 1) / thr, thr, 0, stream>>>(ei, E, N, counts);
    int nb_scan = (N + 1023) / 1024;  // 20
    scan1<<<nb_scan, 1024, 0, stream>>>(counts, row_ptr, bsum, N);
    scan2<<<1, 64, 0, stream>>>(bsum, row_ptr, nb_scan, N);
    scan3<<<nb_scan, 1024, 0, stream>>>(row_ptr, bsum, cursor, N);
    scatter_kernel<<<(Etot + thr - 1) / thr, thr, 0, stream>>>(ei, E, N, cursor, csr_src);

    // ---- layers ----
    int gemm_blocks = Npad / 16;      // 1252
    int ngroups = (N + 3) / 4;        // 5000
    for (int l = 0; l < L; l++) {
        gemm_f16<<<gemm_blocks, 256, 0, stream>>>(
            xt, wt + (size_t)l * D * D,
            att_src + (size_t)l * H * C, att_dst + (size_t)l * H * C,
            hp, a_s, a_d, Npad);
        gat_aggregate<<<4 * ngroups, 256, 0, stream>>>(
            hp, a_s, a_d, row_ptr, csr_src, biases + (size_t)l * D, xt, N, Npad, ngroups);
    }

    // ---- pool + head ----
    col_sum_f16<<<nb_pool, thr, 0, stream>>>(xt, partial, N, rows_per_blk);
    final_kernel<<<1, thr, 0, stream>>>(partial, Wout, bout, out, 1.0f / (float)N, nb_pool);
}

// Round 11
// 324.468 us; speedup vs baseline: 1.4387x; 1.0332x over previous
//
#include <hip/hip_runtime.h>
#include <hip/hip_bf16.h>

#define H 4
#define C 64
#define D 256
#define NEG_SLOPE 0.2f
#define LCAP 256
#define ESHIFT 8.0f

typedef _Float16 half_t;
typedef __attribute__((ext_vector_type(8))) _Float16 half8v;
typedef __attribute__((ext_vector_type(4))) float f32x4;

// Tiled ("fragment-linear") layout for MFMA operand matrices:
//   panel = 16 rows; within panel, half-offset(r,c) = (c>>5)*512 + ((c>>3)&3)*128 + r*8 + (c&7)
//   => a wave's fragment load for k-slab s is CONTIGUOUS: panel*4096 + s*512 + lane*8.
// hp / a_s / a_d are HEAD-MAJOR: hp[h][n][64], a_s[h][n] -- per-head working set
// (2.56MB) fits one XCD's 4MiB L2 under the head-phased aggregation grid.

// c_lo += f16lo(w)*a; c_hi += f16hi(w)*a  -- exact f32 fma with f16 source (no cvt)
__device__ inline void fma_mix_pair(float& clo, float& chi, unsigned wu, float a) {
    asm("v_fma_mix_f32 %0, %2, %3, %0 op_sel_hi:[1,0,0]\n\t"
        "v_fma_mix_f32 %1, %2, %3, %1 op_sel:[1,0,0] op_sel_hi:[1,0,0]"
        : "+v"(clo), "+v"(chi)
        : "v"(wu), "v"(a));
}

// ---------------- CSR build ----------------
__global__ void count_kernel(const int* __restrict__ ei, int E, int N, int* __restrict__ counts) {
    int i = blockIdx.x * blockDim.x + threadIdx.x;
    if (i >= E + N) return;
    int d = (i < E) ? ei[E + i] : (i - E);
    atomicAdd(&counts[d], 1);
}

__global__ __launch_bounds__(1024) void scan1(const int* __restrict__ counts,
                                              int* __restrict__ row_ptr,
                                              int* __restrict__ bsum, int N) {
    __shared__ int wsum[16];
    int tid = threadIdx.x, lane = tid & 63, wid = tid >> 6;
    int idx = blockIdx.x * 1024 + tid;
    int v = (idx < N) ? counts[idx] : 0;
    int val = v;
    #pragma unroll
    for (int o = 1; o < 64; o <<= 1) {
        int t = __shfl_up(val, o);
        if (lane >= o) val += t;
    }
    if (lane == 63) wsum[wid] = val;
    __syncthreads();
    int woff = 0;
    #pragma unroll
    for (int w = 0; w < 16; w++) woff += (w < wid) ? wsum[w] : 0;
    if (idx < N) row_ptr[idx] = woff + val - v;
    if (tid == 1023) bsum[blockIdx.x] = woff + val;
}

__global__ void scan2(int* __restrict__ bsum, int* __restrict__ row_ptr, int nb, int N) {
    int lane = threadIdx.x;
    int v = (lane < nb) ? bsum[lane] : 0;
    int val = v;
    #pragma unroll
    for (int o = 1; o < 64; o <<= 1) {
        int t = __shfl_up(val, o);
        if (lane >= o) val += t;
    }
    if (lane < nb) bsum[lane] = val - v;
    if (lane == 63) row_ptr[N] = val;
}

__global__ __launch_bounds__(1024) void scan3(int* __restrict__ row_ptr,
                                              const int* __restrict__ bsum,
                                              int* __restrict__ cursor, int N) {
    int idx = blockIdx.x * 1024 + threadIdx.x;
    if (idx >= N) return;
    int r = row_ptr[idx] + bsum[blockIdx.x];
    row_ptr[idx] = r;
    cursor[idx] = r;
}

__global__ void scatter_kernel(const int* __restrict__ ei, int E, int N,
                               int* __restrict__ cursor, int* __restrict__ csr_src) {
    int i = blockIdx.x * blockDim.x + threadIdx.x;
    if (i >= E + N) return;
    int s, d;
    if (i < E) { s = ei[i]; d = ei[E + i]; }
    else       { s = d = i - E; }
    int pos = atomicAdd(&cursor[d], 1);
    csr_src[pos] = s;
}

// ---------------- fp32 -> f16 tiled conversions ----------------
__global__ void conv_x(const float* __restrict__ in, half_t* __restrict__ xt, int total) {
    int t = blockIdx.x * blockDim.x + threadIdx.x;
    if (t >= total) return;
    int i = t >> 5, o = t & 31;
    const float* src = in + (size_t)i * 256 + o * 8;
    float4 v0 = *(const float4*)src;
    float4 v1 = *(const float4*)(src + 4);
    half_t q[8] __attribute__((aligned(16)));
    q[0] = (half_t)v0.x; q[1] = (half_t)v0.y; q[2] = (half_t)v0.z; q[3] = (half_t)v0.w;
    q[4] = (half_t)v1.x; q[5] = (half_t)v1.y; q[6] = (half_t)v1.z; q[7] = (half_t)v1.w;
    size_t dst = (size_t)(i >> 4) * 4096 + (o >> 2) * 512 + (o & 3) * 128 + (i & 15) * 8;
    *(half8v*)(xt + dst) = *(half8v*)q;
}

__global__ void conv_w(const float* __restrict__ W, half_t* __restrict__ wt, int total) {
    int idx = blockIdx.x * blockDim.x + threadIdx.x;
    if (idx >= total) return;   // total = L*4*4*8*64
    int Lr = idx & 63;
    int s  = (idx >> 6) & 7;
    int cb = (idx >> 9) & 3;
    int h  = (idx >> 11) & 3;
    int l  = idx >> 13;
    int col = h * 64 + cb * 16 + (Lr & 15);
    int k0  = 32 * s + (Lr >> 4) * 8;
    half_t q[8] __attribute__((aligned(16)));
    #pragma unroll
    for (int j = 0; j < 8; j++)
        q[j] = (half_t)W[(size_t)l * 65536 + (size_t)(k0 + j) * 256 + col];
    *(half8v*)(wt + (size_t)idx * 8) = *(half8v*)q;
}

// ---------------- f16 MFMA GEMM + fused attention scores ----------------
// grid Npad/16 (=1252); block = 16 rows x 256 cols; wave = head = 16 rows x 64 cols.
__global__ __launch_bounds__(256) void gemm_f16(
    const half_t* __restrict__ At, const half_t* __restrict__ Wt,
    const float* __restrict__ asrc, const float* __restrict__ adst,
    half_t* __restrict__ hp, float* __restrict__ as_out, float* __restrict__ ad_out,
    int Npad) {
    int wv = threadIdx.x >> 6, lane = threadIdx.x & 63;
    int h = wv;                    // wave == head
    int r0 = blockIdx.x * 16;
    int rlo = lane & 15;
    const half_t* pa = At + (size_t)blockIdx.x * 4096 + lane * 8;   // + s*512
    const half_t* pb = Wt + (size_t)h * 16384 + lane * 8;           // + cb*4096 + s*512

    f32x4 acc[4];
    #pragma unroll
    for (int cb = 0; cb < 4; cb++) acc[cb] = (f32x4){0.f, 0.f, 0.f, 0.f};

    half8v A0, B0[4], A1, B1[4];

    A0 = *(const half8v*)(pa);
    #pragma unroll
    for (int i = 0; i < 4; i++) B0[i] = *(const half8v*)(pb + i * 4096);

    #pragma unroll
    for (int s = 0; s < 8; s += 2) {
        A1 = *(const half8v*)(pa + (s + 1) * 512);
        #pragma unroll
        for (int i = 0; i < 4; i++) B1[i] = *(const half8v*)(pb + i * 4096 + (s + 1) * 512);
        #pragma unroll
        for (int cb = 0; cb < 4; cb++)
            acc[cb] = __builtin_amdgcn_mfma_f32_16x16x32_f16(A0, B0[cb], acc[cb], 0, 0, 0);
        if (s < 6) {
            A0 = *(const half8v*)(pa + (s + 2) * 512);
            #pragma unroll
            for (int i = 0; i < 4; i++) B0[i] = *(const half8v*)(pb + i * 4096 + (s + 2) * 512);
        }
        #pragma unroll
        for (int cb = 0; cb < 4; cb++)
            acc[cb] = __builtin_amdgcn_mfma_f32_16x16x32_f16(A1, B1[cb], acc[cb], 0, 0, 0);
    }

    // hp HEAD-MAJOR: hp[h][row][ch]: ch = cb*16 + rlo, row = r0 + (lane>>4)*4 + i
    int rbase = r0 + ((lane >> 4) << 2);
    half_t* hph = hp + (size_t)h * Npad * 64;
    #pragma unroll
    for (int cb = 0; cb < 4; cb++) {
        #pragma unroll
        for (int i = 0; i < 4; i++)
            hph[(size_t)(rbase + i) * 64 + cb * 16 + rlo] = (half_t)acc[cb][i];
    }

    // fused a_s/a_d for this wave's head (head-major outputs)
    {
        float ps[4] = {0.f, 0.f, 0.f, 0.f};
        float pd[4] = {0.f, 0.f, 0.f, 0.f};
        #pragma unroll
        for (int cb = 0; cb < 4; cb++) {
            float av = asrc[h * 64 + cb * 16 + rlo];
            float dv = adst[h * 64 + cb * 16 + rlo];
            #pragma unroll
            for (int i = 0; i < 4; i++) {
                ps[i] += acc[cb][i] * av;
                pd[i] += acc[cb][i] * dv;
            }
        }
        #pragma unroll
        for (int mask = 1; mask <= 8; mask <<= 1) {
            #pragma unroll
            for (int i = 0; i < 4; i++) {
                ps[i] += __shfl_xor(ps[i], mask);
                pd[i] += __shfl_xor(pd[i], mask);
            }
        }
        if (rlo == 0) {
            #pragma unroll
            for (int i = 0; i < 4; i++) {
                as_out[(size_t)h * Npad + rbase + i] = ps[i];
                ad_out[(size_t)h * Npad + rbase + i] = pd[i];
            }
        }
    }
}

// ---------------- GAT aggregation: head-phased grid, one wave per (node, head) ----------------
// fma_mix phase B: 1 VALU per channel; unguarded full groups + guarded tail.
__global__ __launch_bounds__(256) void gat_aggregate(
    const half_t* __restrict__ hp, const float* __restrict__ as_, const float* __restrict__ ad_,
    const int* __restrict__ row_ptr, const int* __restrict__ csr_src,
    const float* __restrict__ bias, half_t* __restrict__ hnext, int N, int Npad, int ngroups) {
    __shared__ float lds_e[4][LCAP];
    __shared__ int   lds_s[4][LCAP];
    int wv = threadIdx.x >> 6, lane = threadIdx.x & 63;
    int h = blockIdx.x / ngroups;
    int d = (blockIdx.x % ngroups) * 4 + wv;
    if (d >= N) return;
    int r0 = row_ptr[d], deg = row_ptr[d + 1] - r0;
    const float* ash = as_ + (size_t)h * Npad;
    float adv = ad_[(size_t)h * Npad + d];
    const half_t* hph = hp + (size_t)h * Npad * 64;

    if (deg <= LCAP) {
        // phase A: lane-parallel exp + denom (fixed shift cancels in normalization)
        float ssum = 0.f;
        for (int i = lane; i < deg; i += 64) {
            int s = csr_src[r0 + i];
            float e = ash[s] + adv;
            e = e > 0.f ? e : NEG_SLOPE * e;
            float ex = __expf(e - ESHIFT);
            lds_s[wv][i] = s;
            lds_e[wv][i] = ex;
            ssum += ex;
        }
        #pragma unroll
        for (int o = 32; o; o >>= 1) ssum += __shfl_xor(ssum, o);
        float inv = 1.0f / ssum;

        // phase B: lane = (edge_slot es 0..7, chan-octet chq 0..7)
        int es = lane >> 3, chq = lane & 7;
        const half_t* hpb = hph + chq * 8;
        float c0 = 0.f, c1 = 0.f, c2 = 0.f, c3 = 0.f;
        float c4 = 0.f, c5 = 0.f, c6 = 0.f, c7 = 0.f;
        int full = deg >> 3;           // unguarded groups of 8 edges
        int i = 0;
        for (; i + 2 <= full; i += 2) {   // 2 independent loads in flight
            int e0 = i * 8 + es, e1 = e0 + 8;
            int s0 = lds_s[wv][e0], s1 = lds_s[wv][e1];
            float a0 = lds_e[wv][e0], a1 = lds_e[wv][e1];
            uint4 w0 = *(const uint4*)(hpb + (size_t)s0 * 64);
            uint4 w1 = *(const uint4*)(hpb + (size_t)s1 * 64);
            fma_mix_pair(c0, c1, w0.x, a0);
            fma_mix_pair(c2, c3, w0.y, a0);
            fma_mix_pair(c4, c5, w0.z, a0);
            fma_mix_pair(c6, c7, w0.w, a0);
            fma_mix_pair(c0, c1, w1.x, a1);
            fma_mix_pair(c2, c3, w1.y, a1);
            fma_mix_pair(c4, c5, w1.z, a1);
            fma_mix_pair(c6, c7, w1.w, a1);
        }
        if (i < full) {                   // one remaining unguarded group
            int e0 = i * 8 + es;
            int s0 = lds_s[wv][e0];
            float a0 = lds_e[wv][e0];
            uint4 w0 = *(const uint4*)(hpb + (size_t)s0 * 64);
            fma_mix_pair(c0, c1, w0.x, a0);
            fma_mix_pair(c2, c3, w0.y, a0);
            fma_mix_pair(c4, c5, w0.z, a0);
            fma_mix_pair(c6, c7, w0.w, a0);
            i++;
        }
        {                                 // guarded tail (deg & 7 edges)
            int e0 = full * 8 + es;
            if (e0 < deg) {
                int s0 = lds_s[wv][e0];
                float a0 = lds_e[wv][e0];
                uint4 w0 = *(const uint4*)(hpb + (size_t)s0 * 64);
                fma_mix_pair(c0, c1, w0.x, a0);
                fma_mix_pair(c2, c3, w0.y, a0);
                fma_mix_pair(c4, c5, w0.z, a0);
                fma_mix_pair(c6, c7, w0.w, a0);
            }
        }
        // reduce across the 8 edge slots
        #pragma unroll
        for (int o = 8; o <= 32; o <<= 1) {
            c0 += __shfl_xor(c0, o); c1 += __shfl_xor(c1, o);
            c2 += __shfl_xor(c2, o); c3 += __shfl_xor(c3, o);
            c4 += __shfl_xor(c4, o); c5 += __shfl_xor(c5, o);
            c6 += __shfl_xor(c6, o); c7 += __shfl_xor(c7, o);
        }
        if (es == 0) {
            float vv[8] = {c0, c1, c2, c3, c4, c5, c6, c7};
            half_t oh[8] __attribute__((aligned(16)));
            #pragma unroll
            for (int j = 0; j < 8; j++) {
                float v = vv[j] * inv + bias[h * 64 + chq * 8 + j];
                v = v > 0.f ? v : (__expf(v) - 1.0f);   // ELU
                oh[j] = (half_t)v;
            }
            int o = h * 8 + chq;   // col-octet in tiled layout
            size_t dst = (size_t)(d >> 4) * 4096 + (o >> 2) * 512 + (o & 3) * 128 + (d & 15) * 8;
            *(half8v*)(hnext + dst) = *(half8v*)oh;
        }
    } else {
        // fallback (deg > LCAP): recompute path
        float ssum = 0.f;
        for (int i = lane; i < deg; i += 64) {
            int s = csr_src[r0 + i];
            float e = ash[s] + adv;
            e = e > 0.f ? e : NEG_SLOPE * e;
            ssum += __expf(e - ESHIFT);
        }
        #pragma unroll
        for (int o = 32; o; o >>= 1) ssum += __shfl_xor(ssum, o);
        float inv = 1.0f / ssum;
        float acc = 0.f;
        for (int i = 0; i < deg; i++) {
            int s = csr_src[r0 + i];
            float e = ash[s] + adv;
            e = e > 0.f ? e : NEG_SLOPE * e;
            acc += __expf(e - ESHIFT) * (float)hph[(size_t)s * 64 + lane];
        }
        float v = acc * inv + bias[h * 64 + lane];
        v = v > 0.f ? v : (__expf(v) - 1.0f);
        int c = h * 64 + lane;
        size_t dst = (size_t)(d >> 4) * 4096 + (c >> 5) * 512 + ((c >> 3) & 3) * 128 + (d & 15) * 8 + (c & 7);
        hnext[dst] = (half_t)v;
    }
}

// ---------------- pooling + output head ----------------
__global__ __launch_bounds__(256) void col_sum_f16(const half_t* __restrict__ hin,
                                                   float* __restrict__ partial, int N, int rows_per_blk) {
    int c = threadIdx.x;
    int r0 = blockIdx.x * rows_per_blk;
    int r1 = min(r0 + rows_per_blk, N);
    int coff = (c >> 5) * 512 + ((c >> 3) & 3) * 128 + (c & 7);
    float acc = 0.f;
    for (int r = r0; r < r1; r++)
        acc += (float)hin[(size_t)(r >> 4) * 4096 + coff + (r & 15) * 8];
    partial[(size_t)blockIdx.x * 256 + c] = acc;
}

__global__ __launch_bounds__(256) void final_kernel(const float* __restrict__ partial,
                                                    const float* __restrict__ Wout,
                                                    const float* __restrict__ bout,
                                                    float* __restrict__ out, float invN, int nb) {
    __shared__ float gl[256];
    int j = threadIdx.x;
    float s = 0.f;
    for (int b = 0; b < nb; b++) s += partial[(size_t)b * 256 + j];
    gl[j] = s;
    __syncthreads();
    float acc = 0.f;
    for (int i = 0; i < 256; i++) acc += gl[i] * Wout[i * 256 + j];
    out[j] = acc * invN + bout[j];
}

extern "C" void kernel_launch(void* const* d_in, const int* in_sizes, int n_in,
                              void* d_out, int out_size, void* d_ws, size_t ws_size,
                              hipStream_t stream) {
    const float* x       = (const float*)d_in[0];
    const int*   ei      = (const int*)d_in[1];
    const float* Ws      = (const float*)d_in[2];
    const float* att_src = (const float*)d_in[3];
    const float* att_dst = (const float*)d_in[4];
    const float* biases  = (const float*)d_in[5];
    const float* Wout    = (const float*)d_in[6];
    const float* bout    = (const float*)d_in[7];
    float* out = (float*)d_out;

    int N = in_sizes[0] / D;          // 20000
    int E = in_sizes[1] / 2;          // 320000
    int L = in_sizes[2] / (D * D);    // 4
    int Etot = E + N;
    int Npad = (N + 63) & ~63;        // 20032 (1252 panels)

    char* ws = (char*)d_ws;
    size_t off = 0;
    auto alloc = [&](size_t bytes) -> void* {
        void* p = ws + off;
        off = (off + bytes + 255) & ~(size_t)255;
        return p;
    };
    half_t* xt     = (half_t*)alloc((size_t)Npad * D * 2);   // tiled A / h
    half_t* hp     = (half_t*)alloc((size_t)Npad * D * 2);   // head-major hp
    float* a_s     = (float*)alloc((size_t)Npad * H * 4);    // head-major
    float* a_d     = (float*)alloc((size_t)Npad * H * 4);
    half_t* wt     = (half_t*)alloc((size_t)L * D * D * 2);  // fragment-linear W
    int*   counts  = (int*)alloc((size_t)N * 4);
    int*   row_ptr = (int*)alloc((size_t)(N + 1) * 4);
    int*   cursor  = (int*)alloc((size_t)N * 4);
    int*   bsum    = (int*)alloc(64 * 4);
    int*   csr_src = (int*)alloc((size_t)Etot * 4);
    int rows_per_blk = 254;
    int nb_pool = (N + rows_per_blk - 1) / rows_per_blk;     // 79
    float* partial = (float*)alloc((size_t)nb_pool * 256 * 4);
    if (off > ws_size) return;

    int thr = 256;

    // ---- conversions (tiled) ----
    int xtot = N * 32;
    conv_x<<<(xtot + thr - 1) / thr, thr, 0, stream>>>(x, xt, xtot);
    int wtot = L * 4 * 4 * 8 * 64;
    conv_w<<<(wtot + thr - 1) / thr, thr, 0, stream>>>(Ws, wt, wtot);

    // ---- CSR build (parallel scan) ----
    hipMemsetAsync(counts, 0, (size_t)N * 4, stream);
    count_kernel<<<(Etot + thr - 1) / thr, thr, 0, stream>>>(ei, E, N, counts);
    int nb_scan = (N + 1023) / 1024;  // 20
    scan1<<<nb_scan, 1024, 0, stream>>>(counts, row_ptr, bsum, N);
    scan2<<<1, 64, 0, stream>>>(bsum, row_ptr, nb_scan, N);
    scan3<<<nb_scan, 1024, 0, stream>>>(row_ptr, bsum, cursor, N);
    scatter_kernel<<<(Etot + thr - 1) / thr, thr, 0, stream>>>(ei, E, N, cursor, csr_src);

    // ---- layers ----
    int gemm_blocks = Npad / 16;      // 1252
    int ngroups = (N + 3) / 4;        // 5000
    for (int l = 0; l < L; l++) {
        gemm_f16<<<gemm_blocks, 256, 0, stream>>>(
            xt, wt + (size_t)l * D * D,
            att_src + (size_t)l * H * C, att_dst + (size_t)l * H * C,
            hp, a_s, a_d, Npad);
        gat_aggregate<<<4 * ngroups, 256, 0, stream>>>(
            hp, a_s, a_d, row_ptr, csr_src, biases + (size_t)l * D, xt, N, Npad, ngroups);
    }

    // ---- pool + head ----
    col_sum_f16<<<nb_pool, thr, 0, stream>>>(xt, partial, N, rows_per_blk);
    final_kernel<<<1, thr, 0, stream>>>(partial, Wout, bout, out, 1.0f / (float)N, nb_pool);
}

// Round 12
// 305.628 us; speedup vs baseline: 1.5273x; 1.0616x over previous
//
#include <hip/hip_runtime.h>
#include <hip/hip_bf16.h>

#define H 4
#define C 64
#define D 256
#define NEG_SLOPE 0.2f
#define LCAP 256
#define ESHIFT 8.0f

typedef _Float16 half_t;
typedef __attribute__((ext_vector_type(8))) _Float16 half8v;
typedef __attribute__((ext_vector_type(4))) float f32x4;

// Tiled ("fragment-linear") layout for MFMA operand matrices:
//   panel = 16 rows; within panel, half-offset(r,c) = (c>>5)*512 + ((c>>3)&3)*128 + r*8 + (c&7)
//   => a wave's fragment load for k-slab s is CONTIGUOUS: panel*4096 + s*512 + lane*8.
// hp / a_s / a_d are HEAD-MAJOR: hp[h][n][64], a_s[h][n] -- per-head working set
// (2.56MB) fits one XCD's 4MiB L2 under the head-phased aggregation grid.

// c_lo += f16lo(w)*a; c_hi += f16hi(w)*a  -- exact f32 fma with f16 source (no cvt)
__device__ inline void fma_mix_pair(float& clo, float& chi, unsigned wu, float a) {
    asm("v_fma_mix_f32 %0, %2, %3, %0 op_sel_hi:[1,0,0]\n\t"
        "v_fma_mix_f32 %1, %2, %3, %1 op_sel:[1,0,0] op_sel_hi:[1,0,0]"
        : "+v"(clo), "+v"(chi)
        : "v"(wu), "v"(a));
}

// ---------------- CSR build ----------------
__global__ void count_kernel(const int* __restrict__ ei, int E, int N, int* __restrict__ counts) {
    int i = blockIdx.x * blockDim.x + threadIdx.x;
    if (i >= E + N) return;
    int d = (i < E) ? ei[E + i] : (i - E);
    atomicAdd(&counts[d], 1);
}

__global__ __launch_bounds__(1024) void scan1(const int* __restrict__ counts,
                                              int* __restrict__ row_ptr,
                                              int* __restrict__ bsum, int N) {
    __shared__ int wsum[16];
    int tid = threadIdx.x, lane = tid & 63, wid = tid >> 6;
    int idx = blockIdx.x * 1024 + tid;
    int v = (idx < N) ? counts[idx] : 0;
    int val = v;
    #pragma unroll
    for (int o = 1; o < 64; o <<= 1) {
        int t = __shfl_up(val, o);
        if (lane >= o) val += t;
    }
    if (lane == 63) wsum[wid] = val;
    __syncthreads();
    int woff = 0;
    #pragma unroll
    for (int w = 0; w < 16; w++) woff += (w < wid) ? wsum[w] : 0;
    if (idx < N) row_ptr[idx] = woff + val - v;
    if (tid == 1023) bsum[blockIdx.x] = woff + val;
}

__global__ void scan2(int* __restrict__ bsum, int* __restrict__ row_ptr, int nb, int N) {
    int lane = threadIdx.x;
    int v = (lane < nb) ? bsum[lane] : 0;
    int val = v;
    #pragma unroll
    for (int o = 1; o < 64; o <<= 1) {
        int t = __shfl_up(val, o);
        if (lane >= o) val += t;
    }
    if (lane < nb) bsum[lane] = val - v;
    if (lane == 63) row_ptr[N] = val;
}

__global__ __launch_bounds__(1024) void scan3(int* __restrict__ row_ptr,
                                              const int* __restrict__ bsum,
                                              int* __restrict__ cursor, int N) {
    int idx = blockIdx.x * 1024 + threadIdx.x;
    if (idx >= N) return;
    int r = row_ptr[idx] + bsum[blockIdx.x];
    row_ptr[idx] = r;
    cursor[idx] = r;
}

__global__ void scatter_kernel(const int* __restrict__ ei, int E, int N,
                               int* __restrict__ cursor, int* __restrict__ csr_src) {
    int i = blockIdx.x * blockDim.x + threadIdx.x;
    if (i >= E + N) return;
    int s, d;
    if (i < E) { s = ei[i]; d = ei[E + i]; }
    else       { s = d = i - E; }
    int pos = atomicAdd(&cursor[d], 1);
    csr_src[pos] = s;
}

// ---------------- fp32 -> f16 tiled conversions ----------------
__global__ void conv_x(const float* __restrict__ in, half_t* __restrict__ xt, int total) {
    int t = blockIdx.x * blockDim.x + threadIdx.x;
    if (t >= total) return;
    int i = t >> 5, o = t & 31;
    const float* src = in + (size_t)i * 256 + o * 8;
    float4 v0 = *(const float4*)src;
    float4 v1 = *(const float4*)(src + 4);
    half_t q[8] __attribute__((aligned(16)));
    q[0] = (half_t)v0.x; q[1] = (half_t)v0.y; q[2] = (half_t)v0.z; q[3] = (half_t)v0.w;
    q[4] = (half_t)v1.x; q[5] = (half_t)v1.y; q[6] = (half_t)v1.z; q[7] = (half_t)v1.w;
    size_t dst = (size_t)(i >> 4) * 4096 + (o >> 2) * 512 + (o & 3) * 128 + (i & 15) * 8;
    *(half8v*)(xt + dst) = *(half8v*)q;
}

__global__ void conv_w(const float* __restrict__ W, half_t* __restrict__ wt, int total) {
    int idx = blockIdx.x * blockDim.x + threadIdx.x;
    if (idx >= total) return;   // total = L*4*4*8*64
    int Lr = idx & 63;
    int s  = (idx >> 6) & 7;
    int cb = (idx >> 9) & 3;
    int h  = (idx >> 11) & 3;
    int l  = idx >> 13;
    int col = h * 64 + cb * 16 + (Lr & 15);
    int k0  = 32 * s + (Lr >> 4) * 8;
    half_t q[8] __attribute__((aligned(16)));
    #pragma unroll
    for (int j = 0; j < 8; j++)
        q[j] = (half_t)W[(size_t)l * 65536 + (size_t)(k0 + j) * 256 + col];
    *(half8v*)(wt + (size_t)idx * 8) = *(half8v*)q;
}

// ---------------- f16 MFMA GEMM + fused attention scores ----------------
// grid Npad/16 (=1252); block = 16 rows x 256 cols; wave = head = 16 rows x 64 cols.
__global__ __launch_bounds__(256) void gemm_f16(
    const half_t* __restrict__ At, const half_t* __restrict__ Wt,
    const float* __restrict__ asrc, const float* __restrict__ adst,
    half_t* __restrict__ hp, float* __restrict__ as_out, float* __restrict__ ad_out,
    int Npad) {
    int wv = threadIdx.x >> 6, lane = threadIdx.x & 63;
    int h = wv;                    // wave == head
    int r0 = blockIdx.x * 16;
    int rlo = lane & 15;
    const half_t* pa = At + (size_t)blockIdx.x * 4096 + lane * 8;   // + s*512
    const half_t* pb = Wt + (size_t)h * 16384 + lane * 8;           // + cb*4096 + s*512

    f32x4 acc[4];
    #pragma unroll
    for (int cb = 0; cb < 4; cb++) acc[cb] = (f32x4){0.f, 0.f, 0.f, 0.f};

    half8v A0, B0[4], A1, B1[4];

    A0 = *(const half8v*)(pa);
    #pragma unroll
    for (int i = 0; i < 4; i++) B0[i] = *(const half8v*)(pb + i * 4096);

    #pragma unroll
    for (int s = 0; s < 8; s += 2) {
        A1 = *(const half8v*)(pa + (s + 1) * 512);
        #pragma unroll
        for (int i = 0; i < 4; i++) B1[i] = *(const half8v*)(pb + i * 4096 + (s + 1) * 512);
        #pragma unroll
        for (int cb = 0; cb < 4; cb++)
            acc[cb] = __builtin_amdgcn_mfma_f32_16x16x32_f16(A0, B0[cb], acc[cb], 0, 0, 0);
        if (s < 6) {
            A0 = *(const half8v*)(pa + (s + 2) * 512);
            #pragma unroll
            for (int i = 0; i < 4; i++) B0[i] = *(const half8v*)(pb + i * 4096 + (s + 2) * 512);
        }
        #pragma unroll
        for (int cb = 0; cb < 4; cb++)
            acc[cb] = __builtin_amdgcn_mfma_f32_16x16x32_f16(A1, B1[cb], acc[cb], 0, 0, 0);
    }

    // hp HEAD-MAJOR: hp[h][row][ch]: ch = cb*16 + rlo, row = r0 + (lane>>4)*4 + i
    int rbase = r0 + ((lane >> 4) << 2);
    half_t* hph = hp + (size_t)h * Npad * 64;
    #pragma unroll
    for (int cb = 0; cb < 4; cb++) {
        #pragma unroll
        for (int i = 0; i < 4; i++)
            hph[(size_t)(rbase + i) * 64 + cb * 16 + rlo] = (half_t)acc[cb][i];
    }

    // fused a_s/a_d for this wave's head (head-major outputs)
    {
        float ps[4] = {0.f, 0.f, 0.f, 0.f};
        float pd[4] = {0.f, 0.f, 0.f, 0.f};
        #pragma unroll
        for (int cb = 0; cb < 4; cb++) {
            float av = asrc[h * 64 + cb * 16 + rlo];
            float dv = adst[h * 64 + cb * 16 + rlo];
            #pragma unroll
            for (int i = 0; i < 4; i++) {
                ps[i] += acc[cb][i] * av;
                pd[i] += acc[cb][i] * dv;
            }
        }
        #pragma unroll
        for (int mask = 1; mask <= 8; mask <<= 1) {
            #pragma unroll
            for (int i = 0; i < 4; i++) {
                ps[i] += __shfl_xor(ps[i], mask);
                pd[i] += __shfl_xor(pd[i], mask);
            }
        }
        if (rlo == 0) {
            #pragma unroll
            for (int i = 0; i < 4; i++) {
                as_out[(size_t)h * Npad + rbase + i] = ps[i];
                ad_out[(size_t)h * Npad + rbase + i] = pd[i];
            }
        }
    }
}

// ---------------- GAT aggregation: head-phased grid, one wave per (node, head) ----------------
// phase B: fma_mix + fused denominator (asum rides the channel reduce);
// epilogue: full-lane (cndmask channel select + per-lane ELU, LDS repack, half8 store).
__global__ __launch_bounds__(256) void gat_aggregate(
    const half_t* __restrict__ hp, const float* __restrict__ as_, const float* __restrict__ ad_,
    const int* __restrict__ row_ptr, const int* __restrict__ csr_src,
    const float* __restrict__ bias, half_t* __restrict__ hnext, int N, int Npad, int ngroups) {
    __shared__ float lds_e[4][LCAP];
    __shared__ int   lds_s[4][LCAP];
    __shared__ half_t lds_o[4][64];
    int wv = threadIdx.x >> 6, lane = threadIdx.x & 63;
    int h = blockIdx.x / ngroups;
    int d = (blockIdx.x % ngroups) * 4 + wv;
    if (d >= N) return;
    int r0 = row_ptr[d], deg = row_ptr[d + 1] - r0;
    const float* ash = as_ + (size_t)h * Npad;
    float adv = ad_[(size_t)h * Npad + d];
    const half_t* hph = hp + (size_t)h * Npad * 64;

    if (deg <= LCAP) {
        // phase A: exp into LDS (no reduce here; denominator fused into phase B)
        for (int i = lane; i < deg; i += 64) {
            int s = csr_src[r0 + i];
            float e = ash[s] + adv;
            e = e > 0.f ? e : NEG_SLOPE * e;
            lds_s[wv][i] = s;
            lds_e[wv][i] = __expf(e - ESHIFT);
        }

        // phase B: lane = (edge_slot es 0..7, chan-octet chq 0..7)
        int es = lane >> 3, chq = lane & 7;
        const half_t* hpb = hph + chq * 8;
        float c0 = 0.f, c1 = 0.f, c2 = 0.f, c3 = 0.f;
        float c4 = 0.f, c5 = 0.f, c6 = 0.f, c7 = 0.f;
        float asum = 0.f;
        int full = deg >> 3;           // unguarded groups of 8 edges
        int i = 0;
        for (; i + 2 <= full; i += 2) {   // 2 independent loads in flight
            int e0 = i * 8 + es, e1 = e0 + 8;
            int s0 = lds_s[wv][e0], s1 = lds_s[wv][e1];
            float a0 = lds_e[wv][e0], a1 = lds_e[wv][e1];
            uint4 w0 = *(const uint4*)(hpb + (size_t)s0 * 64);
            uint4 w1 = *(const uint4*)(hpb + (size_t)s1 * 64);
            asum += a0 + a1;
            fma_mix_pair(c0, c1, w0.x, a0);
            fma_mix_pair(c2, c3, w0.y, a0);
            fma_mix_pair(c4, c5, w0.z, a0);
            fma_mix_pair(c6, c7, w0.w, a0);
            fma_mix_pair(c0, c1, w1.x, a1);
            fma_mix_pair(c2, c3, w1.y, a1);
            fma_mix_pair(c4, c5, w1.z, a1);
            fma_mix_pair(c6, c7, w1.w, a1);
        }
        if (i < full) {                   // one remaining unguarded group
            int e0 = i * 8 + es;
            int s0 = lds_s[wv][e0];
            float a0 = lds_e[wv][e0];
            uint4 w0 = *(const uint4*)(hpb + (size_t)s0 * 64);
            asum += a0;
            fma_mix_pair(c0, c1, w0.x, a0);
            fma_mix_pair(c2, c3, w0.y, a0);
            fma_mix_pair(c4, c5, w0.z, a0);
            fma_mix_pair(c6, c7, w0.w, a0);
        }
        {                                 // guarded tail (deg & 7 edges)
            int e0 = full * 8 + es;
            if (e0 < deg) {
                int s0 = lds_s[wv][e0];
                float a0 = lds_e[wv][e0];
                uint4 w0 = *(const uint4*)(hpb + (size_t)s0 * 64);
                asum += a0;
                fma_mix_pair(c0, c1, w0.x, a0);
                fma_mix_pair(c2, c3, w0.y, a0);
                fma_mix_pair(c4, c5, w0.z, a0);
                fma_mix_pair(c6, c7, w0.w, a0);
            }
        }
        // joint reduce (channels + denominator) across the 8 edge slots
        #pragma unroll
        for (int o = 8; o <= 32; o <<= 1) {
            c0 += __shfl_xor(c0, o); c1 += __shfl_xor(c1, o);
            c2 += __shfl_xor(c2, o); c3 += __shfl_xor(c3, o);
            c4 += __shfl_xor(c4, o); c5 += __shfl_xor(c5, o);
            c6 += __shfl_xor(c6, o); c7 += __shfl_xor(c7, o);
            asum += __shfl_xor(asum, o);
        }
        // full-lane epilogue: lane (es,chq) handles channel chq*8+es
        float inv = 1.0f / asum;
        float t0 = (es & 1) ? c1 : c0;
        float t1 = (es & 1) ? c3 : c2;
        float t2 = (es & 1) ? c5 : c4;
        float t3 = (es & 1) ? c7 : c6;
        float u0 = (es & 2) ? t1 : t0;
        float u1 = (es & 2) ? t3 : t2;
        float v  = (es & 4) ? u1 : u0;
        int ch = chq * 8 + es;
        v = v * inv + bias[h * 64 + ch];
        v = v > 0.f ? v : (__expf(v) - 1.0f);   // ELU
        lds_o[wv][ch] = (half_t)v;
        if (es == 0) {   // 8 lanes: chq -> octet
            half8v ov = *(half8v*)&lds_o[wv][chq * 8];
            int o = h * 8 + chq;   // col-octet in tiled layout
            size_t dst = (size_t)(d >> 4) * 4096 + (o >> 2) * 512 + (o & 3) * 128 + (d & 15) * 8;
            *(half8v*)(hnext + dst) = ov;
        }
    } else {
        // fallback (deg > LCAP): recompute path
        float ssum = 0.f;
        for (int i = lane; i < deg; i += 64) {
            int s = csr_src[r0 + i];
            float e = ash[s] + adv;
            e = e > 0.f ? e : NEG_SLOPE * e;
            ssum += __expf(e - ESHIFT);
        }
        #pragma unroll
        for (int o = 32; o; o >>= 1) ssum += __shfl_xor(ssum, o);
        float inv = 1.0f / ssum;
        float acc = 0.f;
        for (int i = 0; i < deg; i++) {
            int s = csr_src[r0 + i];
            float e = ash[s] + adv;
            e = e > 0.f ? e : NEG_SLOPE * e;
            acc += __expf(e - ESHIFT) * (float)hph[(size_t)s * 64 + lane];
        }
        float v = acc * inv + bias[h * 64 + lane];
        v = v > 0.f ? v : (__expf(v) - 1.0f);
        int c = h * 64 + lane;
        size_t dst = (size_t)(d >> 4) * 4096 + (c >> 5) * 512 + ((c >> 3) & 3) * 128 + (d & 15) * 8 + (c & 7);
        hnext[dst] = (half_t)v;
    }
}

// ---------------- pooling + output head ----------------
__global__ __launch_bounds__(256) void col_sum_f16(const half_t* __restrict__ hin,
                                                   float* __restrict__ partial, int N, int rows_per_blk) {
    int c = threadIdx.x;
    int r0 = blockIdx.x * rows_per_blk;
    int r1 = min(r0 + rows_per_blk, N);
    int coff = (c >> 5) * 512 + ((c >> 3) & 3) * 128 + (c & 7);
    float acc = 0.f;
    for (int r = r0; r < r1; r++)
        acc += (float)hin[(size_t)(r >> 4) * 4096 + coff + (r & 15) * 8];
    partial[(size_t)blockIdx.x * 256 + c] = acc;
}

__global__ __launch_bounds__(256) void final_kernel(const float* __restrict__ partial,
                                                    const float* __restrict__ Wout,
                                                    const float* __restrict__ bout,
                                                    float* __restrict__ out, float invN, int nb) {
    __shared__ float gl[256];
    int j = threadIdx.x;
    float s = 0.f;
    for (int b = 0; b < nb; b++) s += partial[(size_t)b * 256 + j];
    gl[j] = s;
    __syncthreads();
    float acc = 0.f;
    for (int i = 0; i < 256; i++) acc += gl[i] * Wout[i * 256 + j];
    out[j] = acc * invN + bout[j];
}

extern "C" void kernel_launch(void* const* d_in, const int* in_sizes, int n_in,
                              void* d_out, int out_size, void* d_ws, size_t ws_size,
                              hipStream_t stream) {
    const float* x       = (const float*)d_in[0];
    const int*   ei      = (const int*)d_in[1];
    const float* Ws      = (const float*)d_in[2];
    const float* att_src = (const float*)d_in[3];
    const float* att_dst = (const float*)d_in[4];
    const float* biases  = (const float*)d_in[5];
    const float* Wout    = (const float*)d_in[6];
    const float* bout    = (const float*)d_in[7];
    float* out = (float*)d_out;

    int N = in_sizes[0] / D;          // 20000
    int E = in_sizes[1] / 2;          // 320000
    int L = in_sizes[2] / (D * D);    // 4
    int Etot = E + N;
    int Npad = (N + 63) & ~63;        // 20032 (1252 panels)

    char* ws = (char*)d_ws;
    size_t off = 0;
    auto alloc = [&](size_t bytes) -> void* {
        void* p = ws + off;
        off = (off + bytes + 255) & ~(size_t)255;
        return p;
    };
    half_t* xt     = (half_t*)alloc((size_t)Npad * D * 2);   // tiled A / h
    half_t* hp     = (half_t*)alloc((size_t)Npad * D * 2);   // head-major hp
    float* a_s     = (float*)alloc((size_t)Npad * H * 4);    // head-major
    float* a_d     = (float*)alloc((size_t)Npad * H * 4);
    half_t* wt     = (half_t*)alloc((size_t)L * D * D * 2);  // fragment-linear W
    int*   counts  = (int*)alloc((size_t)N * 4);
    int*   row_ptr = (int*)alloc((size_t)(N + 1) * 4);
    int*   cursor  = (int*)alloc((size_t)N * 4);
    int*   bsum    = (int*)alloc(64 * 4);
    int*   csr_src = (int*)alloc((size_t)Etot * 4);
    int rows_per_blk = 254;
    int nb_pool = (N + rows_per_blk - 1) / rows_per_blk;     // 79
    float* partial = (float*)alloc((size_t)nb_pool * 256 * 4);
    if (off > ws_size) return;

    int thr = 256;

    // ---- conversions (tiled) ----
    int xtot = N * 32;
    conv_x<<<(xtot + thr - 1) / thr, thr, 0, stream>>>(x, xt, xtot);
    int wtot = L * 4 * 4 * 8 * 64;
    conv_w<<<(wtot + thr - 1) / thr, thr, 0, stream>>>(Ws, wt, wtot);

    // ---- CSR build (parallel scan) ----
    hipMemsetAsync(counts, 0, (size_t)N * 4, stream);
    count_kernel<<<(Etot + thr - 1) / thr, thr, 0, stream>>>(ei, E, N, counts);
    int nb_scan = (N + 1023) / 1024;  // 20
    scan1<<<nb_scan, 1024, 0, stream>>>(counts, row_ptr, bsum, N);
    scan2<<<1, 64, 0, stream>>>(bsum, row_ptr, nb_scan, N);
    scan3<<<nb_scan, 1024, 0, stream>>>(row_ptr, bsum, cursor, N);
    scatter_kernel<<<(Etot + thr - 1) / thr, thr, 0, stream>>>(ei, E, N, cursor, csr_src);

    // ---- layers ----
    int gemm_blocks = Npad / 16;      // 1252
    int ngroups = (N + 3) / 4;        // 5000
    for (int l = 0; l < L; l++) {
        gemm_f16<<<gemm_blocks, 256, 0, stream>>>(
            xt, wt + (size_t)l * D * D,
            att_src + (size_t)l * H * C, att_dst + (size_t)l * H * C,
            hp, a_s, a_d, Npad);
        gat_aggregate<<<4 * ngroups, 256, 0, stream>>>(
            hp, a_s, a_d, row_ptr, csr_src, biases + (size_t)l * D, xt, N, Npad, ngroups);
    }

    // ---- pool + head ----
    col_sum_f16<<<nb_pool, thr, 0, stream>>>(xt, partial, N, rows_per_blk);
    final_kernel<<<1, thr, 0, stream>>>(partial, Wout, bout, out, 1.0f / (float)N, nb_pool);
}

// Round 13
// 274.531 us; speedup vs baseline: 1.7004x; 1.1133x over previous
//
#include <hip/hip_runtime.h>
#include <hip/hip_bf16.h>

#define H 4
#define C 64
#define D 256
#define NEG_SLOPE 0.2f
#define ESHIFT 8.0f

typedef _Float16 half_t;
typedef __attribute__((ext_vector_type(8))) _Float16 half8v;
typedef __attribute__((ext_vector_type(4))) float f32x4;

// Tiled ("fragment-linear") layout for MFMA operand matrices:
//   panel = 16 rows; half-offset(r,c) = (c>>5)*512 + ((c>>3)&3)*128 + r*8 + (c&7)
//   => a wave's fragment load for k-slab s is CONTIGUOUS: panel*4096 + s*512 + lane*8.
// hp is HEAD-MAJOR: hp[h][n][64].  a_s / a_d are NODE-MAJOR: a_s[n][4] (float4/node).

// c_lo += f16lo(w)*a; c_hi += f16hi(w)*a  -- exact f32 fma with f16 source (no cvt)
__device__ inline void fma_mix_pair(float& clo, float& chi, unsigned wu, float a) {
    asm("v_fma_mix_f32 %0, %2, %3, %0 op_sel_hi:[1,0,0]\n\t"
        "v_fma_mix_f32 %1, %2, %3, %1 op_sel:[1,0,0] op_sel_hi:[1,0,0]"
        : "+v"(clo), "+v"(chi)
        : "v"(wu), "v"(a));
}

// ---------------- CSR build ----------------
__global__ void count_kernel(const int* __restrict__ ei, int E, int N, int* __restrict__ counts) {
    int i = blockIdx.x * blockDim.x + threadIdx.x;
    if (i >= E + N) return;
    int d = (i < E) ? ei[E + i] : (i - E);
    atomicAdd(&counts[d], 1);
}

__global__ __launch_bounds__(1024) void scan1(const int* __restrict__ counts,
                                              int* __restrict__ row_ptr,
                                              int* __restrict__ bsum, int N) {
    __shared__ int wsum[16];
    int tid = threadIdx.x, lane = tid & 63, wid = tid >> 6;
    int idx = blockIdx.x * 1024 + tid;
    int v = (idx < N) ? counts[idx] : 0;
    int val = v;
    #pragma unroll
    for (int o = 1; o < 64; o <<= 1) {
        int t = __shfl_up(val, o);
        if (lane >= o) val += t;
    }
    if (lane == 63) wsum[wid] = val;
    __syncthreads();
    int woff = 0;
    #pragma unroll
    for (int w = 0; w < 16; w++) woff += (w < wid) ? wsum[w] : 0;
    if (idx < N) row_ptr[idx] = woff + val - v;
    if (tid == 1023) bsum[blockIdx.x] = woff + val;
}

__global__ void scan2(int* __restrict__ bsum, int* __restrict__ row_ptr, int nb, int N) {
    int lane = threadIdx.x;
    int v = (lane < nb) ? bsum[lane] : 0;
    int val = v;
    #pragma unroll
    for (int o = 1; o < 64; o <<= 1) {
        int t = __shfl_up(val, o);
        if (lane >= o) val += t;
    }
    if (lane < nb) bsum[lane] = val - v;
    if (lane == 63) row_ptr[N] = val;
}

__global__ __launch_bounds__(1024) void scan3(int* __restrict__ row_ptr,
                                              const int* __restrict__ bsum,
                                              int* __restrict__ cursor, int N) {
    int idx = blockIdx.x * 1024 + threadIdx.x;
    if (idx >= N) return;
    int r = row_ptr[idx] + bsum[blockIdx.x];
    row_ptr[idx] = r;
    cursor[idx] = r;
}

__global__ void scatter_kernel(const int* __restrict__ ei, int E, int N,
                               int* __restrict__ cursor, int* __restrict__ csr_src) {
    int i = blockIdx.x * blockDim.x + threadIdx.x;
    if (i >= E + N) return;
    int s, d;
    if (i < E) { s = ei[i]; d = ei[E + i]; }
    else       { s = d = i - E; }
    int pos = atomicAdd(&cursor[d], 1);
    csr_src[pos] = s;
}

// ---------------- fp32 -> f16 tiled conversions ----------------
__global__ void conv_x(const float* __restrict__ in, half_t* __restrict__ xt, int total) {
    int t = blockIdx.x * blockDim.x + threadIdx.x;
    if (t >= total) return;
    int i = t >> 5, o = t & 31;
    const float* src = in + (size_t)i * 256 + o * 8;
    float4 v0 = *(const float4*)src;
    float4 v1 = *(const float4*)(src + 4);
    half_t q[8] __attribute__((aligned(16)));
    q[0] = (half_t)v0.x; q[1] = (half_t)v0.y; q[2] = (half_t)v0.z; q[3] = (half_t)v0.w;
    q[4] = (half_t)v1.x; q[5] = (half_t)v1.y; q[6] = (half_t)v1.z; q[7] = (half_t)v1.w;
    size_t dst = (size_t)(i >> 4) * 4096 + (o >> 2) * 512 + (o & 3) * 128 + (i & 15) * 8;
    *(half8v*)(xt + dst) = *(half8v*)q;
}

__global__ void conv_w(const float* __restrict__ W, half_t* __restrict__ wt, int total) {
    int idx = blockIdx.x * blockDim.x + threadIdx.x;
    if (idx >= total) return;   // total = L*4*4*8*64
    int Lr = idx & 63;
    int s  = (idx >> 6) & 7;
    int cb = (idx >> 9) & 3;
    int h  = (idx >> 11) & 3;
    int l  = idx >> 13;
    int col = h * 64 + cb * 16 + (Lr & 15);
    int k0  = 32 * s + (Lr >> 4) * 8;
    half_t q[8] __attribute__((aligned(16)));
    #pragma unroll
    for (int j = 0; j < 8; j++)
        q[j] = (half_t)W[(size_t)l * 65536 + (size_t)(k0 + j) * 256 + col];
    *(half8v*)(wt + (size_t)idx * 8) = *(half8v*)q;
}

// ---------------- f16 MFMA GEMM + fused attention scores ----------------
// grid (Npad/16)*4 blocks: block = (panel p, head h); 4 waves = 4 col-quarters (cb).
// Wave = 16 rows x 16 cols; A frag shared across waves via L1; ~20k waves for TLP.
__global__ __launch_bounds__(256) void gemm_f16(
    const half_t* __restrict__ At, const half_t* __restrict__ Wt,
    const float* __restrict__ asrc, const float* __restrict__ adst,
    half_t* __restrict__ hp, float* __restrict__ as_out, float* __restrict__ ad_out,
    int Npad) {
    __shared__ float sp[4][16], sd[4][16];
    int cb = threadIdx.x >> 6, lane = threadIdx.x & 63;
    int p = blockIdx.x >> 2, h = blockIdx.x & 3;
    int rlo = lane & 15;
    const half_t* pa = At + (size_t)p * 4096 + lane * 8;                        // + s*512
    const half_t* pb = Wt + (size_t)h * 16384 + (size_t)cb * 4096 + lane * 8;   // + s*512

    f32x4 acc = (f32x4){0.f, 0.f, 0.f, 0.f};
    half8v A0, B0, A1, B1;
    A0 = *(const half8v*)(pa);
    B0 = *(const half8v*)(pb);
    #pragma unroll
    for (int s = 0; s < 8; s += 2) {
        A1 = *(const half8v*)(pa + (s + 1) * 512);
        B1 = *(const half8v*)(pb + (s + 1) * 512);
        acc = __builtin_amdgcn_mfma_f32_16x16x32_f16(A0, B0, acc, 0, 0, 0);
        if (s < 6) {
            A0 = *(const half8v*)(pa + (s + 2) * 512);
            B0 = *(const half8v*)(pb + (s + 2) * 512);
        }
        acc = __builtin_amdgcn_mfma_f32_16x16x32_f16(A1, B1, acc, 0, 0, 0);
    }

    // hp HEAD-MAJOR store: row = p*16 + q*4 + i, ch = cb*16 + rlo
    int q = lane >> 4;
    half_t* hph = hp + (size_t)h * Npad * 64;
    int grow = p * 16 + q * 4;
    #pragma unroll
    for (int i = 0; i < 4; i++)
        hph[(size_t)(grow + i) * 64 + cb * 16 + rlo] = (half_t)acc[i];

    // score partials for this 16-col strip
    {
        float av = asrc[h * 64 + cb * 16 + rlo];
        float dv = adst[h * 64 + cb * 16 + rlo];
        float ps[4], pd[4];
        #pragma unroll
        for (int i = 0; i < 4; i++) { ps[i] = acc[i] * av; pd[i] = acc[i] * dv; }
        #pragma unroll
        for (int mask = 1; mask <= 8; mask <<= 1) {
            #pragma unroll
            for (int i = 0; i < 4; i++) {
                ps[i] += __shfl_xor(ps[i], mask);
                pd[i] += __shfl_xor(pd[i], mask);
            }
        }
        if (rlo == 0) {
            #pragma unroll
            for (int i = 0; i < 4; i++) {
                sp[cb][q * 4 + i] = ps[i];
                sd[cb][q * 4 + i] = pd[i];
            }
        }
    }
    __syncthreads();
    if (threadIdx.x < 16) {
        int r = threadIdx.x;
        float s_ = sp[0][r] + sp[1][r] + sp[2][r] + sp[3][r];
        float d_ = sd[0][r] + sd[1][r] + sd[2][r] + sd[3][r];
        as_out[(size_t)(p * 16 + r) * 4 + h] = s_;
        ad_out[(size_t)(p * 16 + r) * 4 + h] = d_;
    }
}

// ---------------- GAT aggregation: ONE wave per node, all 4 heads ----------------
// Phase A: lane = edge (deg<=64): 1 csr + 1 float4 a_s load, 4 exps -> packed LDS.
// Phase B: lane = (head hh 0..3, slot es 0..1, ch-octet chq 0..7); fma_mix gather.
// Reduce: single xor-8 stage (9 regs). Epilogue: es==0 lanes store their octet.
#define AGG_BODY(g)                                                          \
    {                                                                        \
        int e_ = 2 * (g) + es;                                               \
        int s_ = __float_as_int(pk[wv][e_][0]);                              \
        float a_ = pk[wv][e_][4 + hh];                                       \
        const uint4 w_ = *(const uint4*)(hpb + (size_t)s_ * 64);             \
        asum += a_;                                                          \
        fma_mix_pair(c0, c1, w_.x, a_);                                      \
        fma_mix_pair(c2, c3, w_.y, a_);                                      \
        fma_mix_pair(c4, c5, w_.z, a_);                                      \
        fma_mix_pair(c6, c7, w_.w, a_);                                      \
    }

__global__ __launch_bounds__(256) void gat_aggregate(
    const half_t* __restrict__ hp, const float* __restrict__ as_, const float* __restrict__ ad_,
    const int* __restrict__ row_ptr, const int* __restrict__ csr_src,
    const float* __restrict__ bias, half_t* __restrict__ hnext, int N, int Npad) {
    __shared__ float pk[4][64][8];   // [wave][edge][{s_bits, -, -, -, e0,e1,e2,e3}]
    int wv = threadIdx.x >> 6, lane = threadIdx.x & 63;
    int d = blockIdx.x * 4 + wv;
    if (d >= N) return;
    int r0 = row_ptr[d], deg = row_ptr[d + 1] - r0;
    float4 adv = *(const float4*)&ad_[(size_t)d * 4];

    if (deg <= 64) {
        // phase A
        if (lane < deg) {
            int s = csr_src[r0 + lane];
            float4 as4 = *(const float4*)&as_[(size_t)s * 4];
            float e0 = as4.x + adv.x, e1 = as4.y + adv.y;
            float e2 = as4.z + adv.z, e3 = as4.w + adv.w;
            e0 = e0 > 0.f ? e0 : NEG_SLOPE * e0;
            e1 = e1 > 0.f ? e1 : NEG_SLOPE * e1;
            e2 = e2 > 0.f ? e2 : NEG_SLOPE * e2;
            e3 = e3 > 0.f ? e3 : NEG_SLOPE * e3;
            float4 ex;
            ex.x = __expf(e0 - ESHIFT);
            ex.y = __expf(e1 - ESHIFT);
            ex.z = __expf(e2 - ESHIFT);
            ex.w = __expf(e3 - ESHIFT);
            pk[wv][lane][0] = __int_as_float(s);
            *(float4*)&pk[wv][lane][4] = ex;
        }

        // phase B
        int hh = lane >> 4;
        int es = (lane >> 3) & 1;
        int chq = lane & 7;
        const half_t* hpb = hp + (size_t)hh * Npad * 64 + chq * 8;
        float c0 = 0.f, c1 = 0.f, c2 = 0.f, c3 = 0.f;
        float c4 = 0.f, c5 = 0.f, c6 = 0.f, c7 = 0.f;
        float asum = 0.f;
        int full = deg >> 1;
        int g = 0;
        for (; g + 4 <= full; g += 4) {   // 4 gathers in flight
            AGG_BODY(g) AGG_BODY(g + 1) AGG_BODY(g + 2) AGG_BODY(g + 3)
        }
        for (; g < full; g++) { AGG_BODY(g) }
        if ((deg & 1) && es == 0) {       // odd tail: es==0 half handles last edge
            int e_ = deg - 1;
            int s_ = __float_as_int(pk[wv][e_][0]);
            float a_ = pk[wv][e_][4 + hh];
            const uint4 w_ = *(const uint4*)(hpb + (size_t)s_ * 64);
            asum += a_;
            fma_mix_pair(c0, c1, w_.x, a_);
            fma_mix_pair(c2, c3, w_.y, a_);
            fma_mix_pair(c4, c5, w_.z, a_);
            fma_mix_pair(c6, c7, w_.w, a_);
        }
        // single-stage reduce across the 2 slots
        c0 += __shfl_xor(c0, 8); c1 += __shfl_xor(c1, 8);
        c2 += __shfl_xor(c2, 8); c3 += __shfl_xor(c3, 8);
        c4 += __shfl_xor(c4, 8); c5 += __shfl_xor(c5, 8);
        c6 += __shfl_xor(c6, 8); c7 += __shfl_xor(c7, 8);
        asum += __shfl_xor(asum, 8);
        // epilogue: es==0 lanes (hh,chq) own octet o = hh*8+chq
        if (!(lane & 8)) {
            float inv = 1.0f / asum;
            int o = hh * 8 + chq;
            const float* bp = bias + o * 8;
            float vv[8] = {c0, c1, c2, c3, c4, c5, c6, c7};
            half_t oh[8] __attribute__((aligned(16)));
            #pragma unroll
            for (int j = 0; j < 8; j++) {
                float v = vv[j] * inv + bp[j];
                v = v > 0.f ? v : (__expf(v) - 1.0f);   // ELU
                oh[j] = (half_t)v;
            }
            size_t dst = (size_t)(d >> 4) * 4096 + (o >> 2) * 512 + (o & 3) * 128 + (d & 15) * 8;
            *(half8v*)(hnext + dst) = *(half8v*)oh;
        }
    } else {
        // fallback (deg > 64): per-head serial recompute (rare/never for this data)
        float advA[4] = {adv.x, adv.y, adv.z, adv.w};
        #pragma unroll
        for (int hh = 0; hh < 4; hh++) {
            float advh = advA[hh];
            float ssum = 0.f;
            for (int i = lane; i < deg; i += 64) {
                int s = csr_src[r0 + i];
                float e = as_[(size_t)s * 4 + hh] + advh;
                e = e > 0.f ? e : NEG_SLOPE * e;
                ssum += __expf(e - ESHIFT);
            }
            #pragma unroll
            for (int o = 32; o; o >>= 1) ssum += __shfl_xor(ssum, o);
            float inv = 1.0f / ssum;
            const half_t* hph = hp + (size_t)hh * Npad * 64;
            float acc = 0.f;
            for (int i = 0; i < deg; i++) {
                int s = csr_src[r0 + i];
                float e = as_[(size_t)s * 4 + hh] + advh;
                e = e > 0.f ? e : NEG_SLOPE * e;
                acc += __expf(e - ESHIFT) * (float)hph[(size_t)s * 64 + lane];
            }
            float v = acc * inv + bias[hh * 64 + lane];
            v = v > 0.f ? v : (__expf(v) - 1.0f);
            int c = hh * 64 + lane;
            size_t dst = (size_t)(d >> 4) * 4096 + (c >> 5) * 512 + ((c >> 3) & 3) * 128 + (d & 15) * 8 + (c & 7);
            hnext[dst] = (half_t)v;
        }
    }
}

// ---------------- pooling + output head ----------------
__global__ __launch_bounds__(256) void col_sum_f16(const half_t* __restrict__ hin,
                                                   float* __restrict__ partial, int N, int rows_per_blk) {
    int c = threadIdx.x;
    int r0 = blockIdx.x * rows_per_blk;
    int r1 = min(r0 + rows_per_blk, N);
    int coff = (c >> 5) * 512 + ((c >> 3) & 3) * 128 + (c & 7);
    float acc = 0.f;
    for (int r = r0; r < r1; r++)
        acc += (float)hin[(size_t)(r >> 4) * 4096 + coff + (r & 15) * 8];
    partial[(size_t)blockIdx.x * 256 + c] = acc;
}

__global__ __launch_bounds__(256) void final_kernel(const float* __restrict__ partial,
                                                    const float* __restrict__ Wout,
                                                    const float* __restrict__ bout,
                                                    float* __restrict__ out, float invN, int nb) {
    __shared__ float gl[256];
    int j = threadIdx.x;
    float s = 0.f;
    for (int b = 0; b < nb; b++) s += partial[(size_t)b * 256 + j];
    gl[j] = s;
    __syncthreads();
    float acc = 0.f;
    for (int i = 0; i < 256; i++) acc += gl[i] * Wout[i * 256 + j];
    out[j] = acc * invN + bout[j];
}

extern "C" void kernel_launch(void* const* d_in, const int* in_sizes, int n_in,
                              void* d_out, int out_size, void* d_ws, size_t ws_size,
                              hipStream_t stream) {
    const float* x       = (const float*)d_in[0];
    const int*   ei      = (const int*)d_in[1];
    const float* Ws      = (const float*)d_in[2];
    const float* att_src = (const float*)d_in[3];
    const float* att_dst = (const float*)d_in[4];
    const float* biases  = (const float*)d_in[5];
    const float* Wout    = (const float*)d_in[6];
    const float* bout    = (const float*)d_in[7];
    float* out = (float*)d_out;

    int N = in_sizes[0] / D;          // 20000
    int E = in_sizes[1] / 2;          // 320000
    int L = in_sizes[2] / (D * D);    // 4
    int Etot = E + N;
    int Npad = (N + 63) & ~63;        // 20032 (1252 panels)

    char* ws = (char*)d_ws;
    size_t off = 0;
    auto alloc = [&](size_t bytes) -> void* {
        void* p = ws + off;
        off = (off + bytes + 255) & ~(size_t)255;
        return p;
    };
    half_t* xt     = (half_t*)alloc((size_t)Npad * D * 2);   // tiled A / h
    half_t* hp     = (half_t*)alloc((size_t)Npad * D * 2);   // head-major hp
    float* a_s     = (float*)alloc((size_t)Npad * H * 4);    // node-major [n][4]
    float* a_d     = (float*)alloc((size_t)Npad * H * 4);
    half_t* wt     = (half_t*)alloc((size_t)L * D * D * 2);  // fragment-linear W
    int*   counts  = (int*)alloc((size_t)N * 4);
    int*   row_ptr = (int*)alloc((size_t)(N + 1) * 4);
    int*   cursor  = (int*)alloc((size_t)N * 4);
    int*   bsum    = (int*)alloc(64 * 4);
    int*   csr_src = (int*)alloc((size_t)Etot * 4);
    int rows_per_blk = 254;
    int nb_pool = (N + rows_per_blk - 1) / rows_per_blk;     // 79
    float* partial = (float*)alloc((size_t)nb_pool * 256 * 4);
    if (off > ws_size) return;

    int thr = 256;

    // ---- conversions (tiled) ----
    int xtot = N * 32;
    conv_x<<<(xtot + thr - 1) / thr, thr, 0, stream>>>(x, xt, xtot);
    int wtot = L * 4 * 4 * 8 * 64;
    conv_w<<<(wtot + thr - 1) / thr, thr, 0, stream>>>(Ws, wt, wtot);

    // ---- CSR build (parallel scan) ----
    hipMemsetAsync(counts, 0, (size_t)N * 4, stream);
    count_kernel<<<(Etot + thr - 1) / thr, thr, 0, stream>>>(ei, E, N, counts);
    int nb_scan = (N + 1023) / 1024;  // 20
    scan1<<<nb_scan, 1024, 0, stream>>>(counts, row_ptr, bsum, N);
    scan2<<<1, 64, 0, stream>>>(bsum, row_ptr, nb_scan, N);
    scan3<<<nb_scan, 1024, 0, stream>>>(row_ptr, bsum, cursor, N);
    scatter_kernel<<<(Etot + thr - 1) / thr, thr, 0, stream>>>(ei, E, N, cursor, csr_src);

    // ---- layers ----
    int gemm_blocks = (Npad / 16) * 4;   // 5008: (panel, head)
    int agg_blocks = (N + 3) / 4;        // 5000: 4 nodes/block, 1 wave/node
    for (int l = 0; l < L; l++) {
        gemm_f16<<<gemm_blocks, 256, 0, stream>>>(
            xt, wt + (size_t)l * D * D,
            att_src + (size_t)l * H * C, att_dst + (size_t)l * H * C,
            hp, a_s, a_d, Npad);
        gat_aggregate<<<agg_blocks, 256, 0, stream>>>(
            hp, a_s, a_d, row_ptr, csr_src, biases + (size_t)l * D, xt, N, Npad);
    }

    // ---- pool + head ----
    col_sum_f16<<<nb_pool, thr, 0, stream>>>(xt, partial, N, rows_per_blk);
    final_kernel<<<1, thr, 0, stream>>>(partial, Wout, bout, out, 1.0f / (float)N, nb_pool);
}

// Round 14
// 269.352 us; speedup vs baseline: 1.7331x; 1.0192x over previous
//
#include <hip/hip_runtime.h>
#include <hip/hip_bf16.h>

#define H 4
#define C 64
#define D 256
#define NEG_SLOPE 0.2f
#define ESHIFT 8.0f

typedef _Float16 half_t;
typedef __attribute__((ext_vector_type(8))) _Float16 half8v;
typedef __attribute__((ext_vector_type(4))) float f32x4;

// Tiled ("fragment-linear") layout for MFMA operand matrices:
//   panel = 16 rows; half-offset(r,c) = (c>>5)*512 + ((c>>3)&3)*128 + r*8 + (c&7)
//   => a wave's fragment load for k-slab s is CONTIGUOUS: panel*4096 + s*512 + lane*8.
// hp is HEAD-MAJOR: hp[h][n][64].  a_s / a_d are NODE-MAJOR: a_s[n][4] (float4/node).

// c_lo += f16lo(w)*a; c_hi += f16hi(w)*a  -- exact f32 fma with f16 source (no cvt)
__device__ inline void fma_mix_pair(float& clo, float& chi, unsigned wu, float a) {
    asm("v_fma_mix_f32 %0, %2, %3, %0 op_sel_hi:[1,0,0]\n\t"
        "v_fma_mix_f32 %1, %2, %3, %1 op_sel:[1,0,0] op_sel_hi:[1,0,0]"
        : "+v"(clo), "+v"(chi)
        : "v"(wu), "v"(a));
}

// ---------------- CSR build ----------------
__global__ void count_kernel(const int* __restrict__ ei, int E, int N, int* __restrict__ counts) {
    int i = blockIdx.x * blockDim.x + threadIdx.x;
    if (i >= E + N) return;
    int d = (i < E) ? ei[E + i] : (i - E);
    atomicAdd(&counts[d], 1);
}

__global__ __launch_bounds__(1024) void scan1(const int* __restrict__ counts,
                                              int* __restrict__ row_ptr,
                                              int* __restrict__ bsum, int N) {
    __shared__ int wsum[16];
    int tid = threadIdx.x, lane = tid & 63, wid = tid >> 6;
    int idx = blockIdx.x * 1024 + tid;
    int v = (idx < N) ? counts[idx] : 0;
    int val = v;
    #pragma unroll
    for (int o = 1; o < 64; o <<= 1) {
        int t = __shfl_up(val, o);
        if (lane >= o) val += t;
    }
    if (lane == 63) wsum[wid] = val;
    __syncthreads();
    int woff = 0;
    #pragma unroll
    for (int w = 0; w < 16; w++) woff += (w < wid) ? wsum[w] : 0;
    if (idx < N) row_ptr[idx] = woff + val - v;
    if (tid == 1023) bsum[blockIdx.x] = woff + val;
}

__global__ void scan2(int* __restrict__ bsum, int* __restrict__ row_ptr, int nb, int N) {
    int lane = threadIdx.x;
    int v = (lane < nb) ? bsum[lane] : 0;
    int val = v;
    #pragma unroll
    for (int o = 1; o < 64; o <<= 1) {
        int t = __shfl_up(val, o);
        if (lane >= o) val += t;
    }
    if (lane < nb) bsum[lane] = val - v;
    if (lane == 63) row_ptr[N] = val;
}

__global__ __launch_bounds__(1024) void scan3(int* __restrict__ row_ptr,
                                              const int* __restrict__ bsum,
                                              int* __restrict__ cursor, int N) {
    int idx = blockIdx.x * 1024 + threadIdx.x;
    if (idx >= N) return;
    int r = row_ptr[idx] + bsum[blockIdx.x];
    row_ptr[idx] = r;
    cursor[idx] = r;
}

__global__ void scatter_kernel(const int* __restrict__ ei, int E, int N,
                               int* __restrict__ cursor, int* __restrict__ csr_src) {
    int i = blockIdx.x * blockDim.x + threadIdx.x;
    if (i >= E + N) return;
    int s, d;
    if (i < E) { s = ei[i]; d = ei[E + i]; }
    else       { s = d = i - E; }
    int pos = atomicAdd(&cursor[d], 1);
    csr_src[pos] = s;
}

// ---------------- fp32 -> f16 tiled conversions ----------------
__global__ void conv_x(const float* __restrict__ in, half_t* __restrict__ xt, int total) {
    int t = blockIdx.x * blockDim.x + threadIdx.x;
    if (t >= total) return;
    int i = t >> 5, o = t & 31;
    const float* src = in + (size_t)i * 256 + o * 8;
    float4 v0 = *(const float4*)src;
    float4 v1 = *(const float4*)(src + 4);
    half_t q[8] __attribute__((aligned(16)));
    q[0] = (half_t)v0.x; q[1] = (half_t)v0.y; q[2] = (half_t)v0.z; q[3] = (half_t)v0.w;
    q[4] = (half_t)v1.x; q[5] = (half_t)v1.y; q[6] = (half_t)v1.z; q[7] = (half_t)v1.w;
    size_t dst = (size_t)(i >> 4) * 4096 + (o >> 2) * 512 + (o & 3) * 128 + (i & 15) * 8;
    *(half8v*)(xt + dst) = *(half8v*)q;
}

__global__ void conv_w(const float* __restrict__ W, half_t* __restrict__ wt, int total) {
    int idx = blockIdx.x * blockDim.x + threadIdx.x;
    if (idx >= total) return;   // total = L*4*4*8*64
    int Lr = idx & 63;
    int s  = (idx >> 6) & 7;
    int cb = (idx >> 9) & 3;
    int h  = (idx >> 11) & 3;
    int l  = idx >> 13;
    int col = h * 64 + cb * 16 + (Lr & 15);
    int k0  = 32 * s + (Lr >> 4) * 8;
    half_t q[8] __attribute__((aligned(16)));
    #pragma unroll
    for (int j = 0; j < 8; j++)
        q[j] = (half_t)W[(size_t)l * 65536 + (size_t)(k0 + j) * 256 + col];
    *(half8v*)(wt + (size_t)idx * 8) = *(half8v*)q;
}

// ---------------- persistent-B f16 MFMA GEMM + fused attention scores ----------------
// grid = (Npad/64 panel-groups) x 4 heads; block = 4 waves = 4 col-quarters of one head.
// Each wave holds its FULL K=256 B-fragment set in registers (8 half8v, loaded once),
// then loops over the group's 4 A-panels: 8 A loads (L1-shared across waves) + 8 MFMA.
__global__ __launch_bounds__(256) void gemm_f16(
    const half_t* __restrict__ At, const half_t* __restrict__ Wt,
    const float* __restrict__ asrc, const float* __restrict__ adst,
    half_t* __restrict__ hp, float* __restrict__ as_out, float* __restrict__ ad_out,
    int Npad) {
    __shared__ float sp[2][4][16], sd[2][4][16];
    int cb = threadIdx.x >> 6, lane = threadIdx.x & 63;
    int h = blockIdx.x & 3, pg = blockIdx.x >> 2;
    int rlo = lane & 15, q = lane >> 4;
    const half_t* pb = Wt + (size_t)h * 16384 + (size_t)cb * 4096 + lane * 8;

    half8v B[8];
    #pragma unroll
    for (int s = 0; s < 8; s++) B[s] = *(const half8v*)(pb + s * 512);

    float av = asrc[h * 64 + cb * 16 + rlo];
    float dv = adst[h * 64 + cb * 16 + rlo];
    half_t* hph = hp + (size_t)h * Npad * 64;

    #pragma unroll
    for (int pp = 0; pp < 4; pp++) {
        int p = pg * 4 + pp;
        const half_t* pa = At + (size_t)p * 4096 + lane * 8;

        f32x4 acc = (f32x4){0.f, 0.f, 0.f, 0.f};
        half8v A0 = *(const half8v*)(pa);
        half8v A1;
        #pragma unroll
        for (int s = 0; s < 8; s += 2) {
            A1 = *(const half8v*)(pa + (s + 1) * 512);
            acc = __builtin_amdgcn_mfma_f32_16x16x32_f16(A0, B[s], acc, 0, 0, 0);
            if (s < 6) A0 = *(const half8v*)(pa + (s + 2) * 512);
            acc = __builtin_amdgcn_mfma_f32_16x16x32_f16(A1, B[s + 1], acc, 0, 0, 0);
        }

        // hp HEAD-MAJOR store: row = p*16 + q*4 + i, ch = cb*16 + rlo
        int grow = p * 16 + q * 4;
        #pragma unroll
        for (int i = 0; i < 4; i++)
            hph[(size_t)(grow + i) * 64 + cb * 16 + rlo] = (half_t)acc[i];

        // score partials for this 16-col strip (double-buffered LDS, 1 barrier/panel)
        float ps[4], pd[4];
        #pragma unroll
        for (int i = 0; i < 4; i++) { ps[i] = acc[i] * av; pd[i] = acc[i] * dv; }
        #pragma unroll
        for (int mask = 1; mask <= 8; mask <<= 1) {
            #pragma unroll
            for (int i = 0; i < 4; i++) {
                ps[i] += __shfl_xor(ps[i], mask);
                pd[i] += __shfl_xor(pd[i], mask);
            }
        }
        int par = pp & 1;
        if (rlo == 0) {
            #pragma unroll
            for (int i = 0; i < 4; i++) {
                sp[par][cb][q * 4 + i] = ps[i];
                sd[par][cb][q * 4 + i] = pd[i];
            }
        }
        __syncthreads();
        if (threadIdx.x < 16) {
            int r = threadIdx.x;
            float s_ = sp[par][0][r] + sp[par][1][r] + sp[par][2][r] + sp[par][3][r];
            float d_ = sd[par][0][r] + sd[par][1][r] + sd[par][2][r] + sd[par][3][r];
            as_out[(size_t)(p * 16 + r) * 4 + h] = s_;
            ad_out[(size_t)(p * 16 + r) * 4 + h] = d_;
        }
    }
}

// ---------------- GAT aggregation: ONE wave per node, all 4 heads ----------------
#define AGG_BODY(g)                                                          \
    {                                                                        \
        int e_ = 2 * (g) + es;                                               \
        int s_ = __float_as_int(pk[wv][e_][0]);                              \
        float a_ = pk[wv][e_][4 + hh];                                       \
        const uint4 w_ = *(const uint4*)(hpb + (size_t)s_ * 64);             \
        asum += a_;                                                          \
        fma_mix_pair(c0, c1, w_.x, a_);                                      \
        fma_mix_pair(c2, c3, w_.y, a_);                                      \
        fma_mix_pair(c4, c5, w_.z, a_);                                      \
        fma_mix_pair(c6, c7, w_.w, a_);                                      \
    }

__global__ __launch_bounds__(256) void gat_aggregate(
    const half_t* __restrict__ hp, const float* __restrict__ as_, const float* __restrict__ ad_,
    const int* __restrict__ row_ptr, const int* __restrict__ csr_src,
    const float* __restrict__ bias, half_t* __restrict__ hnext, int N, int Npad) {
    __shared__ float pk[4][64][8];   // [wave][edge][{s_bits, -, -, -, e0,e1,e2,e3}]
    int wv = threadIdx.x >> 6, lane = threadIdx.x & 63;
    int d = blockIdx.x * 4 + wv;
    if (d >= N) return;
    int r0 = row_ptr[d], deg = row_ptr[d + 1] - r0;
    float4 adv = *(const float4*)&ad_[(size_t)d * 4];

    if (deg <= 64) {
        // phase A
        if (lane < deg) {
            int s = csr_src[r0 + lane];
            float4 as4 = *(const float4*)&as_[(size_t)s * 4];
            float e0 = as4.x + adv.x, e1 = as4.y + adv.y;
            float e2 = as4.z + adv.z, e3 = as4.w + adv.w;
            e0 = e0 > 0.f ? e0 : NEG_SLOPE * e0;
            e1 = e1 > 0.f ? e1 : NEG_SLOPE * e1;
            e2 = e2 > 0.f ? e2 : NEG_SLOPE * e2;
            e3 = e3 > 0.f ? e3 : NEG_SLOPE * e3;
            float4 ex;
            ex.x = __expf(e0 - ESHIFT);
            ex.y = __expf(e1 - ESHIFT);
            ex.z = __expf(e2 - ESHIFT);
            ex.w = __expf(e3 - ESHIFT);
            pk[wv][lane][0] = __int_as_float(s);
            *(float4*)&pk[wv][lane][4] = ex;
        }

        // phase B: lane = (head hh, slot es, ch-octet chq)
        int hh = lane >> 4;
        int es = (lane >> 3) & 1;
        int chq = lane & 7;
        const half_t* hpb = hp + (size_t)hh * Npad * 64 + chq * 8;
        float c0 = 0.f, c1 = 0.f, c2 = 0.f, c3 = 0.f;
        float c4 = 0.f, c5 = 0.f, c6 = 0.f, c7 = 0.f;
        float asum = 0.f;
        int full = deg >> 1;
        int g = 0;
        for (; g + 4 <= full; g += 4) {   // 4 gathers in flight
            AGG_BODY(g) AGG_BODY(g + 1) AGG_BODY(g + 2) AGG_BODY(g + 3)
        }
        for (; g < full; g++) { AGG_BODY(g) }
        if ((deg & 1) && es == 0) {       // odd tail
            int e_ = deg - 1;
            int s_ = __float_as_int(pk[wv][e_][0]);
            float a_ = pk[wv][e_][4 + hh];
            const uint4 w_ = *(const uint4*)(hpb + (size_t)s_ * 64);
            asum += a_;
            fma_mix_pair(c0, c1, w_.x, a_);
            fma_mix_pair(c2, c3, w_.y, a_);
            fma_mix_pair(c4, c5, w_.z, a_);
            fma_mix_pair(c6, c7, w_.w, a_);
        }
        // single-stage reduce across the 2 slots
        c0 += __shfl_xor(c0, 8); c1 += __shfl_xor(c1, 8);
        c2 += __shfl_xor(c2, 8); c3 += __shfl_xor(c3, 8);
        c4 += __shfl_xor(c4, 8); c5 += __shfl_xor(c5, 8);
        c6 += __shfl_xor(c6, 8); c7 += __shfl_xor(c7, 8);
        asum += __shfl_xor(asum, 8);
        // epilogue: es==0 lanes (hh,chq) own octet o = hh*8+chq
        if (!(lane & 8)) {
            float inv = 1.0f / asum;
            int o = hh * 8 + chq;
            const float* bp = bias + o * 8;
            float vv[8] = {c0, c1, c2, c3, c4, c5, c6, c7};
            half_t oh[8] __attribute__((aligned(16)));
            #pragma unroll
            for (int j = 0; j < 8; j++) {
                float v = vv[j] * inv + bp[j];
                v = v > 0.f ? v : (__expf(v) - 1.0f);   // ELU
                oh[j] = (half_t)v;
            }
            size_t dst = (size_t)(d >> 4) * 4096 + (o >> 2) * 512 + (o & 3) * 128 + (d & 15) * 8;
            *(half8v*)(hnext + dst) = *(half8v*)oh;
        }
    } else {
        // fallback (deg > 64): per-head serial recompute (rare/never for this data)
        float advA[4] = {adv.x, adv.y, adv.z, adv.w};
        #pragma unroll
        for (int hh = 0; hh < 4; hh++) {
            float advh = advA[hh];
            float ssum = 0.f;
            for (int i = lane; i < deg; i += 64) {
                int s = csr_src[r0 + i];
                float e = as_[(size_t)s * 4 + hh] + advh;
                e = e > 0.f ? e : NEG_SLOPE * e;
                ssum += __expf(e - ESHIFT);
            }
            #pragma unroll
            for (int o = 32; o; o >>= 1) ssum += __shfl_xor(ssum, o);
            float inv = 1.0f / ssum;
            const half_t* hph = hp + (size_t)hh * Npad * 64;
            float acc = 0.f;
            for (int i = 0; i < deg; i++) {
                int s = csr_src[r0 + i];
                float e = as_[(size_t)s * 4 + hh] + advh;
                e = e > 0.f ? e : NEG_SLOPE * e;
                acc += __expf(e - ESHIFT) * (float)hph[(size_t)s * 64 + lane];
            }
            float v = acc * inv + bias[hh * 64 + lane];
            v = v > 0.f ? v : (__expf(v) - 1.0f);
            int c = hh * 64 + lane;
            size_t dst = (size_t)(d >> 4) * 4096 + (c >> 5) * 512 + ((c >> 3) & 3) * 128 + (d & 15) * 8 + (c & 7);
            hnext[dst] = (half_t)v;
        }
    }
}

// ---------------- pooling + output head ----------------
__global__ __launch_bounds__(256) void col_sum_f16(const half_t* __restrict__ hin,
                                                   float* __restrict__ partial, int N, int rows_per_blk) {
    int c = threadIdx.x;
    int r0 = blockIdx.x * rows_per_blk;
    int r1 = min(r0 + rows_per_blk, N);
    int coff = (c >> 5) * 512 + ((c >> 3) & 3) * 128 + (c & 7);
    float acc = 0.f;
    for (int r = r0; r < r1; r++)
        acc += (float)hin[(size_t)(r >> 4) * 4096 + coff + (r & 15) * 8];
    partial[(size_t)blockIdx.x * 256 + c] = acc;
}

__global__ __launch_bounds__(256) void final_kernel(const float* __restrict__ partial,
                                                    const float* __restrict__ Wout,
                                                    const float* __restrict__ bout,
                                                    float* __restrict__ out, float invN, int nb) {
    __shared__ float gl[256];
    int j = threadIdx.x;
    float s = 0.f;
    for (int b = 0; b < nb; b++) s += partial[(size_t)b * 256 + j];
    gl[j] = s;
    __syncthreads();
    float acc = 0.f;
    for (int i = 0; i < 256; i++) acc += gl[i] * Wout[i * 256 + j];
    out[j] = acc * invN + bout[j];
}

extern "C" void kernel_launch(void* const* d_in, const int* in_sizes, int n_in,
                              void* d_out, int out_size, void* d_ws, size_t ws_size,
                              hipStream_t stream) {
    const float* x       = (const float*)d_in[0];
    const int*   ei      = (const int*)d_in[1];
    const float* Ws      = (const float*)d_in[2];
    const float* att_src = (const float*)d_in[3];
    const float* att_dst = (const float*)d_in[4];
    const float* biases  = (const float*)d_in[5];
    const float* Wout    = (const float*)d_in[6];
    const float* bout    = (const float*)d_in[7];
    float* out = (float*)d_out;

    int N = in_sizes[0] / D;          // 20000
    int E = in_sizes[1] / 2;          // 320000
    int L = in_sizes[2] / (D * D);    // 4
    int Etot = E + N;
    int Npad = (N + 63) & ~63;        // 20032 (1252 panels, 313 groups of 4)

    char* ws = (char*)d_ws;
    size_t off = 0;
    auto alloc = [&](size_t bytes) -> void* {
        void* p = ws + off;
        off = (off + bytes + 255) & ~(size_t)255;
        return p;
    };
    half_t* xt     = (half_t*)alloc((size_t)Npad * D * 2);   // tiled A / h
    half_t* hp     = (half_t*)alloc((size_t)Npad * D * 2);   // head-major hp
    float* a_s     = (float*)alloc((size_t)Npad * H * 4);    // node-major [n][4]
    float* a_d     = (float*)alloc((size_t)Npad * H * 4);
    half_t* wt     = (half_t*)alloc((size_t)L * D * D * 2);  // fragment-linear W
    int*   counts  = (int*)alloc((size_t)N * 4);
    int*   row_ptr = (int*)alloc((size_t)(N + 1) * 4);
    int*   cursor  = (int*)alloc((size_t)N * 4);
    int*   bsum    = (int*)alloc(64 * 4);
    int*   csr_src = (int*)alloc((size_t)Etot * 4);
    int rows_per_blk = 254;
    int nb_pool = (N + rows_per_blk - 1) / rows_per_blk;     // 79
    float* partial = (float*)alloc((size_t)nb_pool * 256 * 4);
    if (off > ws_size) return;

    int thr = 256;

    // ---- conversions (tiled) ----
    int xtot = N * 32;
    conv_x<<<(xtot + thr - 1) / thr, thr, 0, stream>>>(x, xt, xtot);
    int wtot = L * 4 * 4 * 8 * 64;
    conv_w<<<(wtot + thr - 1) / thr, thr, 0, stream>>>(Ws, wt, wtot);

    // ---- CSR build (parallel scan) ----
    hipMemsetAsync(counts, 0, (size_t)N * 4, stream);
    count_kernel<<<(Etot + thr - 1) / thr, thr, 0, stream>>>(ei, E, N, counts);
    int nb_scan = (N + 1023) / 1024;  // 20
    scan1<<<nb_scan, 1024, 0, stream>>>(counts, row_ptr, bsum, N);
    scan2<<<1, 64, 0, stream>>>(bsum, row_ptr, nb_scan, N);
    scan3<<<nb_scan, 1024, 0, stream>>>(row_ptr, bsum, cursor, N);
    scatter_kernel<<<(Etot + thr - 1) / thr, thr, 0, stream>>>(ei, E, N, cursor, csr_src);

    // ---- layers ----
    int gemm_blocks = (Npad / 64) * 4;   // 1252: (panel-group, head)
    int agg_blocks = (N + 3) / 4;        // 5000: 4 nodes/block, 1 wave/node
    for (int l = 0; l < L; l++) {
        gemm_f16<<<gemm_blocks, 256, 0, stream>>>(
            xt, wt + (size_t)l * D * D,
            att_src + (size_t)l * H * C, att_dst + (size_t)l * H * C,
            hp, a_s, a_d, Npad);
        gat_aggregate<<<agg_blocks, 256, 0, stream>>>(
            hp, a_s, a_d, row_ptr, csr_src, biases + (size_t)l * D, xt, N, Npad);
    }

    // ---- pool + head ----
    col_sum_f16<<<nb_pool, thr, 0, stream>>>(xt, partial, N, rows_per_blk);
    final_kernel<<<1, thr, 0, stream>>>(partial, Wout, bout, out, 1.0f / (float)N, nb_pool);
}